// Round 14
// baseline (527.864 us; speedup 1.0000x reference)
//
#include <hip/hip_runtime.h>

#define H_ 8
#define B_ 32
#define L_ 1024
#define D_ 64
#define M_ 512
#define NR_ 32768  // B_*L_
#define LOG2E 1.44269504088896340736f

typedef _Float16 half8 __attribute__((ext_vector_type(8)));
typedef _Float16 half4 __attribute__((ext_vector_type(4)));
typedef _Float16 half2v __attribute__((ext_vector_type(2)));
typedef float f32x16 __attribute__((ext_vector_type(16)));
typedef unsigned int uint2v __attribute__((ext_vector_type(2)));
typedef unsigned int uint4v __attribute__((ext_vector_type(4)));

#define MFMA32(A, B, C) __builtin_amdgcn_mfma_f32_32x32x16_f16(A, B, C, 0, 0, 0)

static __device__ __forceinline__ unsigned pkh(float a, float b) {
  return __builtin_bit_cast(unsigned, __builtin_amdgcn_cvt_pkrtz(a, b));
}
// 8B-aligned LDS moves (row strides 36/68 halves are 8B- but not 16B-aligned)
static __device__ __forceinline__ half8 lds_ld8(const _Float16* p) {
  half4 a = *(const half4*)p;
  half4 b = *(const half4*)(p + 4);
  return __builtin_shufflevector(a, b, 0, 1, 2, 3, 4, 5, 6, 7);
}
static __device__ __forceinline__ void lds_st8(_Float16* p, half8 v) {
  *(half4*)p       = __builtin_shufflevector(v, v, 0, 1, 2, 3);
  *(half4*)(p + 4) = __builtin_shufflevector(v, v, 4, 5, 6, 7);
}
struct half2s { _Float16 h, l; };
static __device__ __forceinline__ half2s split1(float x) {
  half2s r;
  r.h = (_Float16)x;
  r.l = (_Float16)(x - (float)r.h);
  return r;
}

// ---------------------------------------------------------------------------
// prep: three small jobs in one launch.
//  blocks [0,384):   pre_w (24,512,64) f32 -> w2t_hi/lo (1536,512) fp16 (transposed)
//  blocks [384,512): post_w (512,512) f32 -> pwt fp16 (transposed)
//  blocks [512,1024): mask (1024,1024) f32 -> mask2 fp16 * log2(e)
// ---------------------------------------------------------------------------
__global__ __launch_bounds__(256) void prep(
    const float* __restrict__ pre_w, _Float16* __restrict__ w2t_hi,
    _Float16* __restrict__ w2t_lo,
    const float* __restrict__ post_w, _Float16* __restrict__ pwt,
    const float* __restrict__ mask, _Float16* __restrict__ mask2)
{
  const int bid = blockIdx.x;
  const int t = threadIdx.x;
  if (bid < 384) {
    const int gid = bid * 256 + t;
    const int cc = gid >> 6;
    const int m0 = (gid & 63) << 3;
    const int g = cc >> 6, d = cc & 63;
    half8 h, l;
    #pragma unroll
    for (int j = 0; j < 8; ++j) {
      half2s s = split1(pre_w[((size_t)g * M_ + m0 + j) * D_ + d]);
      h[j] = s.h;
      l[j] = s.l;
    }
    *(half8*)(w2t_hi + (size_t)cc * M_ + m0) = h;
    *(half8*)(w2t_lo + (size_t)cc * M_ + m0) = l;
  } else if (bid < 512) {
    const int gid = (bid - 384) * 256 + t;
    const int cc = gid >> 6;
    const int m0 = (gid & 63) << 3;
    half8 h;
    #pragma unroll
    for (int j = 0; j < 8; ++j) h[j] = (_Float16)post_w[(size_t)(m0 + j) * M_ + cc];
    *(half8*)(pwt + (size_t)cc * M_ + m0) = h;
  } else {
    const size_t i = (size_t)(bid - 512) * 256 + t;  // per 8 elems
    float4 a = ((const float4*)mask)[i * 2];
    float4 b = ((const float4*)mask)[i * 2 + 1];
    float v[8] = {a.x, a.y, a.z, a.w, b.x, b.y, b.z, b.w};
    half8 h;
    #pragma unroll
    for (int j = 0; j < 8; ++j) h[j] = (_Float16)(v[j] * LOG2E);
    *(half8*)(mask2 + i * 8) = h;
  }
}

// ---------------------------------------------------------------------------
// qkv_fused v3: A-operand fragments loaded DIRECTLY from global into regs
// (8 contiguous f32 per lane per (c,i); hh=0/1 lane pair covers one full
// 64-B line; each element read once; L2/L3-hot across the 12 col-blocks).
// A-path has NO barrier dependency -> issued one k-step ahead, covered by
// MFMA. f32->hi/lo split at consume, under MFMA cover. Only W goes through
// LDS (double-buffered, single barrier/k-step). LDS 36.9 KB (was 73.7).
// ---------------------------------------------------------------------------
__global__ __launch_bounds__(256, 2) void qkv_fused(
    const float* __restrict__ A,
    const _Float16* __restrict__ Whi, const _Float16* __restrict__ Wlo,
    const float* __restrict__ bias,
    _Float16* __restrict__ qh, _Float16* __restrict__ ql,
    _Float16* __restrict__ kh, _Float16* __restrict__ kl,
    _Float16* __restrict__ vt)
{
  __shared__ _Float16 BshS[2][128 * 36];
  __shared__ _Float16 BslS[2][128 * 36];   // 36864 B total

  const bool THREE = blockIdx.x < 8;
  const int t = threadIdx.x;
  const int lane = t & 63, w = t >> 6;
  const int wr = w >> 1, wc = w & 1;
  const int lr = lane & 31, hh = lane >> 5;
  const int col0 = blockIdx.x * 128;
  const int row0 = blockIdx.y * 128;

  const int sr = t >> 2;          // 0..63
  const int so = (t & 3) * 8;     // 0,8,16,24

  const _Float16* Wb  = &Whi[(size_t)(col0 + sr) * M_ + so];
  const _Float16* Wlb = &Wlo[(size_t)(col0 + sr) * M_ + so];
  // per-lane A fragment base: row = row0 + wr*64 + (i*32) + lr, k offset hh*8
  const float* Arow = &A[(size_t)(row0 + wr * 64 + lr) * M_ + hh * 8];

  f32x16 acc[2][2];
  #pragma unroll
  for (int i = 0; i < 2; ++i)
    #pragma unroll
    for (int j = 0; j < 2; ++j)
      #pragma unroll
      for (int r = 0; r < 16; ++r) acc[i][j][r] = 0.f;

  // prologue: A frags for ks=0 (in flight), W slab 0 -> LDS buf0
  float4 ar0[2][2], ar1[2][2];   // [c][i]
  #pragma unroll
  for (int c = 0; c < 2; ++c)
    #pragma unroll
    for (int i = 0; i < 2; ++i) {
      const float* ap = Arow + (size_t)i * 32 * M_ + c * 16;
      ar0[c][i] = *(const float4*)ap;
      ar1[c][i] = *(const float4*)(ap + 4);
    }
  {
    #pragma unroll
    for (int i = 0; i < 2; ++i) {
      half8 bh = *(const half8*)(Wb + (size_t)i * 64 * M_);
      const int r = sr + i * 64;
      lds_st8(&BshS[0][r * 36 + so], bh);
      if (THREE) {
        half8 bl = *(const half8*)(Wlb + (size_t)i * 64 * M_);
        lds_st8(&BslS[0][r * 36 + so], bl);
      }
    }
  }

  for (int ks = 0; ks < 16; ++ks) {
    const int cur = ks & 1;
    const int kn = (ks + 1) * 32;
    __syncthreads();   // W buf[cur] ready

    // W prefetch for next slab (regs; consumed at end of iteration)
    half8 nwh[2], nwl[2];
    if (kn < M_) {
      #pragma unroll
      for (int i = 0; i < 2; ++i) {
        nwh[i] = *(const half8*)(Wb + (size_t)i * 64 * M_ + kn);
        if (THREE) nwl[i] = *(const half8*)(Wlb + (size_t)i * 64 * M_ + kn);
      }
    }

    // W fragments from LDS
    const _Float16* Bsh = BshS[cur];
    const _Float16* Bsl = BslS[cur];
    half8 fbh[2][2], fbl[2][2];   // [c][j]
    #pragma unroll
    for (int c = 0; c < 2; ++c)
      #pragma unroll
      for (int j = 0; j < 2; ++j) {
        const int br = (wc * 64 + j * 32 + lr) * 36 + c * 16 + hh * 8;
        fbh[c][j] = lds_ld8(&Bsh[br]);
        if (THREE) fbl[c][j] = lds_ld8(&Bsl[br]);
      }

    // split current A frags (raw regs freed for the next issue)
    half8 fah[2][2], fal[2][2];
    #pragma unroll
    for (int c = 0; c < 2; ++c)
      #pragma unroll
      for (int i = 0; i < 2; ++i) {
        float v[8] = {ar0[c][i].x, ar0[c][i].y, ar0[c][i].z, ar0[c][i].w,
                      ar1[c][i].x, ar1[c][i].y, ar1[c][i].z, ar1[c][i].w};
        if (THREE) {
          #pragma unroll
          for (int jj = 0; jj < 8; ++jj) {
            half2s s = split1(v[jj]);
            fah[c][i][jj] = s.h;
            fal[c][i][jj] = s.l;
          }
        } else {
          #pragma unroll
          for (int jj = 0; jj < 8; ++jj) fah[c][i][jj] = (_Float16)v[jj];
        }
      }

    // issue next-iteration A frag loads (no barrier dep; covered by MFMA)
    if (kn < M_) {
      #pragma unroll
      for (int c = 0; c < 2; ++c)
        #pragma unroll
        for (int i = 0; i < 2; ++i) {
          const float* ap = Arow + (size_t)i * 32 * M_ + kn + c * 16;
          ar0[c][i] = *(const float4*)ap;
          ar1[c][i] = *(const float4*)(ap + 4);
        }
    }

    __builtin_amdgcn_s_setprio(1);
    #pragma unroll
    for (int c = 0; c < 2; ++c) {
      #pragma unroll
      for (int i = 0; i < 2; ++i)
        #pragma unroll
        for (int j = 0; j < 2; ++j)
          acc[i][j] = MFMA32(fah[c][i], fbh[c][j], acc[i][j]);
      if (THREE) {
        #pragma unroll
        for (int i = 0; i < 2; ++i)
          #pragma unroll
          for (int j = 0; j < 2; ++j)
            acc[i][j] = MFMA32(fah[c][i], fbl[c][j], acc[i][j]);
        #pragma unroll
        for (int i = 0; i < 2; ++i)
          #pragma unroll
          for (int j = 0; j < 2; ++j)
            acc[i][j] = MFMA32(fal[c][i], fbh[c][j], acc[i][j]);
      }
    }
    __builtin_amdgcn_s_setprio(0);

    // store W prefetch into the other buffer
    if (kn < M_) {
      _Float16* Bn  = BshS[cur ^ 1];
      _Float16* Bln = BslS[cur ^ 1];
      #pragma unroll
      for (int i = 0; i < 2; ++i) {
        const int r = sr + i * 64;
        lds_st8(&Bn[r * 36 + so], nwh[i]);
        if (THREE) lds_st8(&Bln[r * 36 + so], nwl[i]);
      }
    }
  }

  #pragma unroll
  for (int j = 0; j < 2; ++j) {
    const int cc = col0 + wc * 64 + j * 32 + lr;
    const int g = cc >> 6;
    const int t3 = g >> 3, hd = g & 7;
    const int d = cc & 63;
    const float bs = bias[cc];
    #pragma unroll
    for (int i = 0; i < 2; ++i) {
      if (THREE) {
        #pragma unroll
        for (int r = 0; r < 16; ++r) {
          const int rrow = row0 + wr * 64 + i * 32 + (r & 3) + 8 * (r >> 2) + 4 * hh;
          const float x = acc[i][j][r] + bs;
          const size_t base = ((size_t)hd * NR_ + rrow) * D_ + d;
          if (t3 == 0) {
            half2s s = split1(x * LOG2E);   // fold log2(e) into Q
            qh[base] = s.h; ql[base] = s.l;
          } else {
            half2s s = split1(x);
            kh[base] = s.h; kl[base] = s.l;
          }
        }
      } else {
        // v: transposed layout, half4 stores along l (consecutive r&3)
        #pragma unroll
        for (int m = 0; m < 4; ++m) {
          const int rbase = row0 + wr * 64 + i * 32 + 8 * m + 4 * hh;
          const int bb = rbase >> 10;
          const int ll = rbase & 1023;
          half4 v4;
          #pragma unroll
          for (int u = 0; u < 4; ++u) v4[u] = (_Float16)(acc[i][j][4 * m + u] + bs);
          *(half4*)(vt + (((size_t)hd * 32 + bb) * 64 + d) * 1024 + ll) = v4;
        }
      }
    }
  }
}

// ---------------------------------------------------------------------------
// attn_mfma v9 (frozen): round-11 structure; l-sum via v_dot2_f32_f16 on the
// packed fp16 P words.
// ---------------------------------------------------------------------------
__global__ __launch_bounds__(256, 3) void attn_mfma(
    const _Float16* __restrict__ qh, const _Float16* __restrict__ ql,
    const _Float16* __restrict__ kh, const _Float16* __restrict__ kl,
    const _Float16* __restrict__ vt,  // (8,32,64,1024) halves: [hd][b][d][l]
    const _Float16* __restrict__ mask2,  // (1024,1024) fp16, pre-scaled log2(e)
    _Float16* __restrict__ outa)      // (32768, 512) fp16
{
  constexpr int ST = 68;              // halves; 8B-aligned rows
  __shared__ _Float16 KhS[2][64 * ST];
  __shared__ _Float16 KlS[2][64 * ST];
  __shared__ _Float16 VtS[2][64 * ST];   // [d][k] row-major

  const int t    = threadIdx.x;
  const int lane = t & 63, w = t >> 6;
  const int lq   = lane & 31, hh = lane >> 5;
  const int qt = blockIdx.y;          // 0..7  (phase-major dispatch)
  const int bh = blockIdx.x;          // 0..255
  const int b  = bh & 31;
  const int hd = bh >> 5;

  const int q_row = qt * 128 + w * 32 + lq;
  const size_t headoff = (size_t)hd * NR_ * D_ + (size_t)b * L_ * D_;

  const size_t qbase = headoff + (size_t)q_row * D_;
  half8 Qhc[4], Qlc[4];
  #pragma unroll
  for (int c = 0; c < 4; ++c) {
    Qhc[c] = *(const half8*)(qh + qbase + c * 16 + hh * 8);
    Qlc[c] = *(const half8*)(ql + qbase + c * 16 + hh * 8);
  }

  const _Float16* Kph = kh + headoff;
  const _Float16* Kpl = kl + headoff;
  const _Float16* Vtp = vt + ((size_t)hd * 32 + b) * (64 * 1024);  // [d][l]
  const _Float16* mrow = mask2 + (size_t)q_row * L_;

  const int srow = t >> 2;            // 0..63
  const int soff = (t & 3) * 16;      // 0,16,32,48 halves

  float m_i = -3.0e38f, l_i = 0.f;
  f32x16 O0, O1;
  #pragma unroll
  for (int i = 0; i < 16; ++i) { O0[i] = 0.f; O1[i] = 0.f; }

  // staging registers (next K/V tile in flight)
  half8 rkh0, rkh1, rkl0, rkl1, rv0, rv1;
  {
    const size_t goff  = (size_t)srow * D_ + soff;        // K tile kt=0
    const size_t goffv = (size_t)srow * 1024 + soff;      // V^T tile kt=0
    rkh0 = *(const half8*)(Kph + goff);
    rkh1 = *(const half8*)(Kph + goff + 8);
    rkl0 = *(const half8*)(Kpl + goff);
    rkl1 = *(const half8*)(Kpl + goff + 8);
    rv0  = *(const half8*)(Vtp + goffv);
    rv1  = *(const half8*)(Vtp + goffv + 8);
  }
  {
    lds_st8(&KhS[0][srow * ST + soff],     rkh0);
    lds_st8(&KhS[0][srow * ST + soff + 8], rkh1);
    lds_st8(&KlS[0][srow * ST + soff],     rkl0);
    lds_st8(&KlS[0][srow * ST + soff + 8], rkl1);
    lds_st8(&VtS[0][srow * ST + soff],     rv0);
    lds_st8(&VtS[0][srow * ST + soff + 8], rv1);
  }

  for (int kt = 0; kt < 16; ++kt) {
    const int cur = kt & 1;

    // mask loads for this kt (fp16, issued BEFORE the barrier; C-init use)
    half4 mc[8];
    #pragma unroll
    for (int m = 0; m < 8; ++m)
      mc[m] = *(const half4*)(mrow + kt * 64 + (m >> 2) * 32 + (m & 3) * 8 + hh * 4);

    __syncthreads();   // buf[cur] complete

    // issue next-tile global loads (consumed at end-of-iter LDS write)
    if (kt + 1 < 16) {
      const size_t goff  = (size_t)((kt + 1) * 64 + srow) * D_ + soff;
      const size_t goffv = (size_t)srow * 1024 + (kt + 1) * 64 + soff;
      rkh0 = *(const half8*)(Kph + goff);
      rkh1 = *(const half8*)(Kph + goff + 8);
      rkl0 = *(const half8*)(Kpl + goff);
      rkl1 = *(const half8*)(Kpl + goff + 8);
      rv0  = *(const half8*)(Vtp + goffv);
      rv1  = *(const half8*)(Vtp + goffv + 8);
    }

    const _Float16* Kh = KhS[cur];
    const _Float16* Kl = KlS[cur];
    const _Float16* Vt = VtS[cur];

    // ---- S^T = K . Q + mask (mask converted into the MFMA C-init) ----
    f32x16 S[2];
    #pragma unroll
    for (int s2 = 0; s2 < 2; ++s2) {
      f32x16 acc;
      #pragma unroll
      for (int m = 0; m < 4; ++m) {
        half4 mv = mc[s2 * 4 + m];
        acc[4 * m + 0] = (float)mv[0];
        acc[4 * m + 1] = (float)mv[1];
        acc[4 * m + 2] = (float)mv[2];
        acc[4 * m + 3] = (float)mv[3];
      }
      #pragma unroll
      for (int c = 0; c < 4; ++c) {
        half8 ah = lds_ld8(&Kh[(s2 * 32 + lq) * ST + c * 16 + hh * 8]);
        half8 al = lds_ld8(&Kl[(s2 * 32 + lq) * ST + c * 16 + hh * 8]);
        __builtin_amdgcn_s_setprio(1);
        acc = MFMA32(ah, Qhc[c], acc);
        acc = MFMA32(ah, Qlc[c], acc);
        acc = MFMA32(al, Qhc[c], acc);
        __builtin_amdgcn_s_setprio(0);
      }
      S[s2] = acc;
    }

    // ---- tile max (max3-friendly tree) ----
    float pm[8];
    #pragma unroll
    for (int g4 = 0; g4 < 8; ++g4) {
      const int s2 = g4 >> 2, m = g4 & 3;
      pm[g4] = fmaxf(fmaxf(S[s2][4 * m + 0], S[s2][4 * m + 1]),
                     fmaxf(S[s2][4 * m + 2], S[s2][4 * m + 3]));
    }
    float tmax = fmaxf(fmaxf(fmaxf(pm[0], pm[1]), fmaxf(pm[2], pm[3])),
                       fmaxf(fmaxf(pm[4], pm[5]), fmaxf(pm[6], pm[7])));
    tmax = fmaxf(tmax, __shfl_xor(tmax, 32, 64));

    // ---- defer-max: only rescale when the tile max grows past m_i + 8 ----
    if (!__all(tmax - m_i <= 8.0f)) {
      float mn = fmaxf(m_i, tmax);
      float sc = exp2f(m_i - mn);
      m_i = mn;
      l_i *= sc;
      O0 = O0 * sc;
      O1 = O1 * sc;
    }

    #pragma unroll
    for (int s2 = 0; s2 < 2; ++s2)
      #pragma unroll
      for (int r = 0; r < 16; ++r)
        S[s2][r] = exp2f(S[s2][r] - m_i);

    // ---- pack P -> fp16 words; l-sum over the PACKED values ----
    unsigned pw[4][4];
    #pragma unroll
    for (int kc = 0; kc < 4; ++kc) {
      const int s2 = kc >> 1, a2 = kc & 1;
      pw[kc][0] = pkh(S[s2][8 * a2 + 0], S[s2][8 * a2 + 1]);
      pw[kc][1] = pkh(S[s2][8 * a2 + 2], S[s2][8 * a2 + 3]);
      pw[kc][2] = pkh(S[s2][8 * a2 + 4], S[s2][8 * a2 + 5]);
      pw[kc][3] = pkh(S[s2][8 * a2 + 6], S[s2][8 * a2 + 7]);
    }
    float rs = 0.f;
#if __has_builtin(__builtin_amdgcn_fdot2)
    {
      half2v one2;
      one2[0] = (_Float16)1.0f;
      one2[1] = (_Float16)1.0f;
      #pragma unroll
      for (int kc = 0; kc < 4; ++kc)
        #pragma unroll
        for (int u = 0; u < 4; ++u)
          rs = __builtin_amdgcn_fdot2(
              __builtin_bit_cast(half2v, pw[kc][u]), one2, rs, false);
    }
#else
    #pragma unroll
    for (int s2 = 0; s2 < 2; ++s2)
      #pragma unroll
      for (int r = 0; r < 16; ++r) rs += S[s2][r];
#endif
    rs += __shfl_xor(rs, 32, 64);
    l_i += rs;

    // ---- O^T += V^T . P^T ; P^T frags via permlane32_swap ----
    #pragma unroll
    for (int kc = 0; kc < 4; ++kc) {
      uint2v r0 = __builtin_amdgcn_permlane32_swap(pw[kc][0], pw[kc][2], false, false);
      uint2v r1 = __builtin_amdgcn_permlane32_swap(pw[kc][1], pw[kc][3], false, false);
      uint4v wv;
      wv.x = r0.x; wv.y = r1.x; wv.z = r0.y; wv.w = r1.y;
      half8 pfrag = __builtin_bit_cast(half8, wv);
      half8 va = lds_ld8(&Vt[lq * ST + kc * 16 + hh * 8]);
      half8 vb = lds_ld8(&Vt[(32 + lq) * ST + kc * 16 + hh * 8]);
      __builtin_amdgcn_s_setprio(1);
      O0 = MFMA32(va, pfrag, O0);
      O1 = MFMA32(vb, pfrag, O1);
      __builtin_amdgcn_s_setprio(0);
    }

    // ---- write next tile into the other buffer ----
    if (kt + 1 < 16) {
      _Float16* Kh2 = KhS[cur ^ 1];
      _Float16* Kl2 = KlS[cur ^ 1];
      _Float16* Vt2 = VtS[cur ^ 1];
      lds_st8(&Kh2[srow * ST + soff],     rkh0);
      lds_st8(&Kh2[srow * ST + soff + 8], rkh1);
      lds_st8(&Kl2[srow * ST + soff],     rkl0);
      lds_st8(&Kl2[srow * ST + soff + 8], rkl1);
      lds_st8(&Vt2[srow * ST + soff],     rv0);
      lds_st8(&Vt2[srow * ST + soff + 8], rv1);
    }
  }

  float inv = 1.0f / l_i;
  _Float16* orow = outa + ((size_t)b * L_ + q_row) * M_ + hd * 64;
  #pragma unroll
  for (int m = 0; m < 4; ++m) {
    half4 v0 = {(_Float16)(O0[4 * m + 0] * inv), (_Float16)(O0[4 * m + 1] * inv),
                (_Float16)(O0[4 * m + 2] * inv), (_Float16)(O0[4 * m + 3] * inv)};
    *(half4*)(orow + m * 8 + hh * 4) = v0;
    half4 v1 = {(_Float16)(O1[4 * m + 0] * inv), (_Float16)(O1[4 * m + 1] * inv),
                (_Float16)(O1[4 * m + 2] * inv), (_Float16)(O1[4 * m + 3] * inv)};
    *(half4*)(orow + 32 + m * 8 + hh * 4) = v1;
  }
}

// ---------------------------------------------------------------------------
// post_mfma: out(32768x512 f32) = attn_h(f16) x pwt(f16) + bias
// ---------------------------------------------------------------------------
__global__ __launch_bounds__(256, 2) void post_mfma(
    const _Float16* __restrict__ Ah, const _Float16* __restrict__ Wt,
    const float* __restrict__ bias, float* __restrict__ C)
{
  __shared__ _Float16 Ash[128 * 36];
  __shared__ _Float16 Bsh[128 * 36];

  const int t = threadIdx.x;
  const int lane = t & 63, w = t >> 6;
  const int wr = w >> 1, wc = w & 1;
  const int lr = lane & 31, hh = lane >> 5;
  const int col0 = blockIdx.x * 128;
  const int row0 = blockIdx.y * 128;

  const int sr = t >> 2;
  const int so = (t & 3) * 8;

  f32x16 acc[2][2];
  #pragma unroll
  for (int i = 0; i < 2; ++i)
    #pragma unroll
    for (int j = 0; j < 2; ++j)
      #pragma unroll
      for (int r = 0; r < 16; ++r) acc[i][j][r] = 0.f;

  half8 rah[2], rbh[2];
  #pragma unroll
  for (int i = 0; i < 2; ++i) {
    rah[i] = *(const half8*)(Ah + (size_t)(row0 + sr + i * 64) * M_ + so);
    rbh[i] = *(const half8*)(Wt + (size_t)(col0 + sr + i * 64) * M_ + so);
  }

  for (int k0 = 0; k0 < M_; k0 += 32) {
    #pragma unroll
    for (int i = 0; i < 2; ++i) {
      int r = sr + i * 64;
      lds_st8(&Ash[r * 36 + so], rah[i]);
      lds_st8(&Bsh[r * 36 + so], rbh[i]);
    }
    __syncthreads();
    if (k0 + 32 < M_) {
      #pragma unroll
      for (int i = 0; i < 2; ++i) {
        rah[i] = *(const half8*)(Ah + (size_t)(row0 + sr + i * 64) * M_ + k0 + 32 + so);
        rbh[i] = *(const half8*)(Wt + (size_t)(col0 + sr + i * 64) * M_ + k0 + 32 + so);
      }
    }
    half8 fah[2][2], fbh[2][2];
    #pragma unroll
    for (int c = 0; c < 2; ++c)
      #pragma unroll
      for (int i = 0; i < 2; ++i) {
        fah[c][i] = lds_ld8(&Ash[(wr * 64 + i * 32 + lr) * 36 + c * 16 + hh * 8]);
        fbh[c][i] = lds_ld8(&Bsh[(wc * 64 + i * 32 + lr) * 36 + c * 16 + hh * 8]);
      }
    __builtin_amdgcn_s_setprio(1);
    #pragma unroll
    for (int c = 0; c < 2; ++c)
      #pragma unroll
      for (int i = 0; i < 2; ++i)
        #pragma unroll
        for (int j = 0; j < 2; ++j)
          acc[i][j] = MFMA32(fah[c][i], fbh[c][j], acc[i][j]);
    __builtin_amdgcn_s_setprio(0);
    __syncthreads();
  }

  #pragma unroll
  for (int j = 0; j < 2; ++j) {
    const int cc = col0 + wc * 64 + j * 32 + lr;
    const float bs = bias[cc];
    #pragma unroll
    for (int i = 0; i < 2; ++i)
      #pragma unroll
      for (int r = 0; r < 16; ++r) {
        const int rrow = row0 + wr * 64 + i * 32 + (r & 3) + 8 * (r >> 2) + 4 * hh;
        C[(size_t)rrow * M_ + cc] = acc[i][j][r] + bs;
      }
  }
}

extern "C" void kernel_launch(void* const* d_in, const int* in_sizes, int n_in,
                              void* d_out, int out_size, void* d_ws, size_t ws_size,
                              hipStream_t stream) {
  const float* inp    = (const float*)d_in[0];
  const float* mask   = (const float*)d_in[1];
  const float* pre_w  = (const float*)d_in[2];
  const float* pre_b  = (const float*)d_in[3];
  const float* post_w = (const float*)d_in[4];
  const float* post_b = (const float*)d_in[5];
  float* out = (float*)d_out;

  const size_t HNE = (size_t)H_ * NR_ * D_;   // 16,777,216

  _Float16* w2t_hi = (_Float16*)d_ws;              // (1536,512)
  _Float16* w2t_lo = w2t_hi + (size_t)1536 * M_;
  _Float16* pwt    = w2t_lo + (size_t)1536 * M_;   // (512,512)
  _Float16* q_hi   = pwt + (size_t)M_ * M_;
  _Float16* q_lo   = q_hi + HNE;
  _Float16* k_hi   = q_lo + HNE;
  _Float16* k_lo   = k_hi + HNE;
  _Float16* v_t    = k_lo + HNE;              // (8,32,64,1024) transposed v
  _Float16* mask2  = v_t + HNE;               // (1024,1024) fp16
  _Float16* attn_h = mask2 + (size_t)L_ * L_; // (32768,512) fp16

  prep<<<1024, 256, 0, stream>>>(pre_w, w2t_hi, w2t_lo, post_w, pwt, mask, mask2);

  qkv_fused<<<dim3(12, 256), 256, 0, stream>>>(
      inp, w2t_hi, w2t_lo, pre_b, q_hi, q_lo, k_hi, k_lo, v_t);

  attn_mfma<<<dim3(256, 8), 256, 0, stream>>>(q_hi, q_lo, k_hi, k_lo, v_t,
                                              mask2, attn_h);

  post_mfma<<<dim3(4, 256), 256, 0, stream>>>(attn_h, pwt, post_b, out);
}

// Round 15
// 459.995 us; speedup vs baseline: 1.1475x; 1.1475x over previous
//
#include <hip/hip_runtime.h>

#define H_ 8
#define B_ 32
#define L_ 1024
#define D_ 64
#define M_ 512
#define NR_ 32768  // B_*L_
#define LOG2E 1.44269504088896340736f

typedef _Float16 half8 __attribute__((ext_vector_type(8)));
typedef _Float16 half4 __attribute__((ext_vector_type(4)));
typedef _Float16 half2v __attribute__((ext_vector_type(2)));
typedef float f32x16 __attribute__((ext_vector_type(16)));
typedef unsigned int uint2v __attribute__((ext_vector_type(2)));
typedef unsigned int uint4v __attribute__((ext_vector_type(4)));

#define MFMA32(A, B, C) __builtin_amdgcn_mfma_f32_32x32x16_f16(A, B, C, 0, 0, 0)

static __device__ __forceinline__ unsigned pkh(float a, float b) {
  return __builtin_bit_cast(unsigned, __builtin_amdgcn_cvt_pkrtz(a, b));
}
// 8B-aligned LDS moves (row strides 36/68 halves are 8B- but not 16B-aligned)
static __device__ __forceinline__ half8 lds_ld8(const _Float16* p) {
  half4 a = *(const half4*)p;
  half4 b = *(const half4*)(p + 4);
  return __builtin_shufflevector(a, b, 0, 1, 2, 3, 4, 5, 6, 7);
}
static __device__ __forceinline__ void lds_st8(_Float16* p, half8 v) {
  *(half4*)p       = __builtin_shufflevector(v, v, 0, 1, 2, 3);
  *(half4*)(p + 4) = __builtin_shufflevector(v, v, 4, 5, 6, 7);
}
struct half2s { _Float16 h, l; };
static __device__ __forceinline__ half2s split1(float x) {
  half2s r;
  r.h = (_Float16)x;
  r.l = (_Float16)(x - (float)r.h);
  return r;
}

// ---------------------------------------------------------------------------
// prep: three small jobs in one launch.
// ---------------------------------------------------------------------------
__global__ __launch_bounds__(256) void prep(
    const float* __restrict__ pre_w, _Float16* __restrict__ w2t_hi,
    _Float16* __restrict__ w2t_lo,
    const float* __restrict__ post_w, _Float16* __restrict__ pwt,
    const float* __restrict__ mask, _Float16* __restrict__ mask2)
{
  const int bid = blockIdx.x;
  const int t = threadIdx.x;
  if (bid < 384) {
    const int gid = bid * 256 + t;
    const int cc = gid >> 6;
    const int m0 = (gid & 63) << 3;
    const int g = cc >> 6, d = cc & 63;
    half8 h, l;
    #pragma unroll
    for (int j = 0; j < 8; ++j) {
      half2s s = split1(pre_w[((size_t)g * M_ + m0 + j) * D_ + d]);
      h[j] = s.h;
      l[j] = s.l;
    }
    *(half8*)(w2t_hi + (size_t)cc * M_ + m0) = h;
    *(half8*)(w2t_lo + (size_t)cc * M_ + m0) = l;
  } else if (bid < 512) {
    const int gid = (bid - 384) * 256 + t;
    const int cc = gid >> 6;
    const int m0 = (gid & 63) << 3;
    half8 h;
    #pragma unroll
    for (int j = 0; j < 8; ++j) h[j] = (_Float16)post_w[(size_t)(m0 + j) * M_ + cc];
    *(half8*)(pwt + (size_t)cc * M_ + m0) = h;
  } else {
    const size_t i = (size_t)(bid - 512) * 256 + t;  // per 8 elems
    float4 a = ((const float4*)mask)[i * 2];
    float4 b = ((const float4*)mask)[i * 2 + 1];
    float v[8] = {a.x, a.y, a.z, a.w, b.x, b.y, b.z, b.w};
    half8 h;
    #pragma unroll
    for (int j = 0; j < 8; ++j) h[j] = (_Float16)(v[j] * LOG2E);
    *(half8*)(mask2 + i * 8) = h;
  }
}

// ---------------------------------------------------------------------------
// qkv_fused v5: round-12 coalesced stage->LDS structure, but 512-thread /
// 8-wave blocks with 64x32 wave tiles. Same block tile (128x128), same
// global+LDS traffic, HALF the per-wave registers (acc 32, frags 48) ->
// 4 waves/SIMD (16 waves/CU) instead of 2 -> latency hiding doubles.
// Column blocks 0..7 (q,k): 3-term hi/lo. Blocks 8..11 (v): 1-term.
// ---------------------------------------------------------------------------
__global__ __launch_bounds__(512, 4) void qkv_fused(
    const float* __restrict__ A,
    const _Float16* __restrict__ Whi, const _Float16* __restrict__ Wlo,
    const float* __restrict__ bias,
    _Float16* __restrict__ qh, _Float16* __restrict__ ql,
    _Float16* __restrict__ kh, _Float16* __restrict__ kl,
    _Float16* __restrict__ vt)
{
  __shared__ _Float16 Ash[128 * 36];
  __shared__ _Float16 Asl[128 * 36];
  __shared__ _Float16 Bsh[128 * 36];
  __shared__ _Float16 Bsl[128 * 36];   // 36864 B

  const bool THREE = blockIdx.x < 8;
  const int t = threadIdx.x;            // 0..511
  const int lane = t & 63, w = t >> 6;  // 8 waves
  const int wr = w >> 2, wc = w & 3;    // 2 x 4 wave grid
  const int lr = lane & 31, hh = lane >> 5;
  const int col0 = blockIdx.x * 128;
  const int row0 = blockIdx.y * 128;

  const int sr = t >> 2;          // 0..127
  const int so = (t & 3) * 8;     // 0,8,16,24

  const float*    Ab  = &A  [(size_t)(row0 + sr) * M_ + so];
  const _Float16* Wb  = &Whi[(size_t)(col0 + sr) * M_ + so];
  const _Float16* Wlb = &Wlo[(size_t)(col0 + sr) * M_ + so];

  f32x16 acc[2];
  #pragma unroll
  for (int i = 0; i < 2; ++i)
    #pragma unroll
    for (int r = 0; r < 16; ++r) acc[i][r] = 0.f;

  // initial prefetch (k-slab 0)
  float4 ra0 = *(const float4*)Ab;
  float4 ra1 = *(const float4*)(Ab + 4);
  half8 rbh = *(const half8*)Wb;
  half8 rbl;
  if (THREE) rbl = *(const half8*)Wlb;

  for (int k0 = 0; k0 < M_; k0 += 32) {
    // convert + store staged regs into LDS
    {
      float v[8] = {ra0.x, ra0.y, ra0.z, ra0.w, ra1.x, ra1.y, ra1.z, ra1.w};
      half8 h, l;
      if (THREE) {
        #pragma unroll
        for (int j = 0; j < 8; ++j) { half2s s = split1(v[j]); h[j] = s.h; l[j] = s.l; }
        lds_st8(&Asl[sr * 36 + so], l);
        lds_st8(&Bsl[sr * 36 + so], rbl);
      } else {
        #pragma unroll
        for (int j = 0; j < 8; ++j) h[j] = (_Float16)v[j];
      }
      lds_st8(&Ash[sr * 36 + so], h);
      lds_st8(&Bsh[sr * 36 + so], rbh);
    }
    __syncthreads();
    if (k0 + 32 < M_) {
      ra0 = *(const float4*)(Ab + k0 + 32);
      ra1 = *(const float4*)(Ab + k0 + 36);
      rbh = *(const half8*)(Wb + k0 + 32);
      if (THREE) rbl = *(const half8*)(Wlb + k0 + 32);
    }

    // fragments: A rows (wr*64 + i*32 + lr), W col (wc*32 + lr)
    half8 fah[2][2], fal[2][2], fbh[2], fbl[2];   // [c][i] / [c]
    #pragma unroll
    for (int c = 0; c < 2; ++c) {
      #pragma unroll
      for (int i = 0; i < 2; ++i) {
        const int ar = (wr * 64 + i * 32 + lr) * 36 + c * 16 + hh * 8;
        fah[c][i] = lds_ld8(&Ash[ar]);
        if (THREE) fal[c][i] = lds_ld8(&Asl[ar]);
      }
      const int br = (wc * 32 + lr) * 36 + c * 16 + hh * 8;
      fbh[c] = lds_ld8(&Bsh[br]);
      if (THREE) fbl[c] = lds_ld8(&Bsl[br]);
    }

    __builtin_amdgcn_s_setprio(1);
    #pragma unroll
    for (int c = 0; c < 2; ++c) {
      #pragma unroll
      for (int i = 0; i < 2; ++i)
        acc[i] = MFMA32(fah[c][i], fbh[c], acc[i]);
      if (THREE) {
        #pragma unroll
        for (int i = 0; i < 2; ++i)
          acc[i] = MFMA32(fah[c][i], fbl[c], acc[i]);
        #pragma unroll
        for (int i = 0; i < 2; ++i)
          acc[i] = MFMA32(fal[c][i], fbh[c], acc[i]);
      }
    }
    __builtin_amdgcn_s_setprio(0);
    __syncthreads();
  }

  // epilogue: wave covers rows [row0+wr*64, +64), cols [col0+wc*32, +32)
  {
    const int cc = col0 + wc * 32 + lr;
    const int g = cc >> 6;
    const int t3 = g >> 3, hd = g & 7;
    const int d = cc & 63;
    const float bs = bias[cc];
    #pragma unroll
    for (int i = 0; i < 2; ++i) {
      if (THREE) {
        #pragma unroll
        for (int r = 0; r < 16; ++r) {
          const int rrow = row0 + wr * 64 + i * 32 + (r & 3) + 8 * (r >> 2) + 4 * hh;
          const float x = acc[i][r] + bs;
          const size_t base = ((size_t)hd * NR_ + rrow) * D_ + d;
          if (t3 == 0) {
            half2s s = split1(x * LOG2E);   // fold log2(e) into Q
            qh[base] = s.h; ql[base] = s.l;
          } else {
            half2s s = split1(x);
            kh[base] = s.h; kl[base] = s.l;
          }
        }
      } else {
        // v: transposed layout, half4 stores along l (consecutive r&3)
        #pragma unroll
        for (int m = 0; m < 4; ++m) {
          const int rbase = row0 + wr * 64 + i * 32 + 8 * m + 4 * hh;
          const int bb = rbase >> 10;
          const int ll = rbase & 1023;
          half4 v4;
          #pragma unroll
          for (int u = 0; u < 4; ++u) v4[u] = (_Float16)(acc[i][4 * m + u] + bs);
          *(half4*)(vt + (((size_t)hd * 32 + bb) * 64 + d) * 1024 + ll) = v4;
        }
      }
    }
  }
}

// ---------------------------------------------------------------------------
// attn_mfma v9 (frozen, 212 us): round-11 structure; l-sum via fdot2.
// ---------------------------------------------------------------------------
__global__ __launch_bounds__(256, 3) void attn_mfma(
    const _Float16* __restrict__ qh, const _Float16* __restrict__ ql,
    const _Float16* __restrict__ kh, const _Float16* __restrict__ kl,
    const _Float16* __restrict__ vt,  // (8,32,64,1024) halves: [hd][b][d][l]
    const _Float16* __restrict__ mask2,  // (1024,1024) fp16, pre-scaled log2(e)
    _Float16* __restrict__ outa)      // (32768, 512) fp16
{
  constexpr int ST = 68;              // halves; 8B-aligned rows
  __shared__ _Float16 KhS[2][64 * ST];
  __shared__ _Float16 KlS[2][64 * ST];
  __shared__ _Float16 VtS[2][64 * ST];   // [d][k] row-major

  const int t    = threadIdx.x;
  const int lane = t & 63, w = t >> 6;
  const int lq   = lane & 31, hh = lane >> 5;
  const int qt = blockIdx.y;          // 0..7  (phase-major dispatch)
  const int bh = blockIdx.x;          // 0..255
  const int b  = bh & 31;
  const int hd = bh >> 5;

  const int q_row = qt * 128 + w * 32 + lq;
  const size_t headoff = (size_t)hd * NR_ * D_ + (size_t)b * L_ * D_;

  const size_t qbase = headoff + (size_t)q_row * D_;
  half8 Qhc[4], Qlc[4];
  #pragma unroll
  for (int c = 0; c < 4; ++c) {
    Qhc[c] = *(const half8*)(qh + qbase + c * 16 + hh * 8);
    Qlc[c] = *(const half8*)(ql + qbase + c * 16 + hh * 8);
  }

  const _Float16* Kph = kh + headoff;
  const _Float16* Kpl = kl + headoff;
  const _Float16* Vtp = vt + ((size_t)hd * 32 + b) * (64 * 1024);  // [d][l]
  const _Float16* mrow = mask2 + (size_t)q_row * L_;

  const int srow = t >> 2;            // 0..63
  const int soff = (t & 3) * 16;      // 0,16,32,48 halves

  float m_i = -3.0e38f, l_i = 0.f;
  f32x16 O0, O1;
  #pragma unroll
  for (int i = 0; i < 16; ++i) { O0[i] = 0.f; O1[i] = 0.f; }

  // staging registers (next K/V tile in flight)
  half8 rkh0, rkh1, rkl0, rkl1, rv0, rv1;
  {
    const size_t goff  = (size_t)srow * D_ + soff;        // K tile kt=0
    const size_t goffv = (size_t)srow * 1024 + soff;      // V^T tile kt=0
    rkh0 = *(const half8*)(Kph + goff);
    rkh1 = *(const half8*)(Kph + goff + 8);
    rkl0 = *(const half8*)(Kpl + goff);
    rkl1 = *(const half8*)(Kpl + goff + 8);
    rv0  = *(const half8*)(Vtp + goffv);
    rv1  = *(const half8*)(Vtp + goffv + 8);
  }
  {
    lds_st8(&KhS[0][srow * ST + soff],     rkh0);
    lds_st8(&KhS[0][srow * ST + soff + 8], rkh1);
    lds_st8(&KlS[0][srow * ST + soff],     rkl0);
    lds_st8(&KlS[0][srow * ST + soff + 8], rkl1);
    lds_st8(&VtS[0][srow * ST + soff],     rv0);
    lds_st8(&VtS[0][srow * ST + soff + 8], rv1);
  }

  for (int kt = 0; kt < 16; ++kt) {
    const int cur = kt & 1;

    // mask loads for this kt (fp16, issued BEFORE the barrier; C-init use)
    half4 mc[8];
    #pragma unroll
    for (int m = 0; m < 8; ++m)
      mc[m] = *(const half4*)(mrow + kt * 64 + (m >> 2) * 32 + (m & 3) * 8 + hh * 4);

    __syncthreads();   // buf[cur] complete

    // issue next-tile global loads (consumed at end-of-iter LDS write)
    if (kt + 1 < 16) {
      const size_t goff  = (size_t)((kt + 1) * 64 + srow) * D_ + soff;
      const size_t goffv = (size_t)srow * 1024 + (kt + 1) * 64 + soff;
      rkh0 = *(const half8*)(Kph + goff);
      rkh1 = *(const half8*)(Kph + goff + 8);
      rkl0 = *(const half8*)(Kpl + goff);
      rkl1 = *(const half8*)(Kpl + goff + 8);
      rv0  = *(const half8*)(Vtp + goffv);
      rv1  = *(const half8*)(Vtp + goffv + 8);
    }

    const _Float16* Kh = KhS[cur];
    const _Float16* Kl = KlS[cur];
    const _Float16* Vt = VtS[cur];

    // ---- S^T = K . Q + mask (mask converted into the MFMA C-init) ----
    f32x16 S[2];
    #pragma unroll
    for (int s2 = 0; s2 < 2; ++s2) {
      f32x16 acc;
      #pragma unroll
      for (int m = 0; m < 4; ++m) {
        half4 mv = mc[s2 * 4 + m];
        acc[4 * m + 0] = (float)mv[0];
        acc[4 * m + 1] = (float)mv[1];
        acc[4 * m + 2] = (float)mv[2];
        acc[4 * m + 3] = (float)mv[3];
      }
      #pragma unroll
      for (int c = 0; c < 4; ++c) {
        half8 ah = lds_ld8(&Kh[(s2 * 32 + lq) * ST + c * 16 + hh * 8]);
        half8 al = lds_ld8(&Kl[(s2 * 32 + lq) * ST + c * 16 + hh * 8]);
        __builtin_amdgcn_s_setprio(1);
        acc = MFMA32(ah, Qhc[c], acc);
        acc = MFMA32(ah, Qlc[c], acc);
        acc = MFMA32(al, Qhc[c], acc);
        __builtin_amdgcn_s_setprio(0);
      }
      S[s2] = acc;
    }

    // ---- tile max (max3-friendly tree) ----
    float pm[8];
    #pragma unroll
    for (int g4 = 0; g4 < 8; ++g4) {
      const int s2 = g4 >> 2, m = g4 & 3;
      pm[g4] = fmaxf(fmaxf(S[s2][4 * m + 0], S[s2][4 * m + 1]),
                     fmaxf(S[s2][4 * m + 2], S[s2][4 * m + 3]));
    }
    float tmax = fmaxf(fmaxf(fmaxf(pm[0], pm[1]), fmaxf(pm[2], pm[3])),
                       fmaxf(fmaxf(pm[4], pm[5]), fmaxf(pm[6], pm[7])));
    tmax = fmaxf(tmax, __shfl_xor(tmax, 32, 64));

    // ---- defer-max: only rescale when the tile max grows past m_i + 8 ----
    if (!__all(tmax - m_i <= 8.0f)) {
      float mn = fmaxf(m_i, tmax);
      float sc = exp2f(m_i - mn);
      m_i = mn;
      l_i *= sc;
      O0 = O0 * sc;
      O1 = O1 * sc;
    }

    #pragma unroll
    for (int s2 = 0; s2 < 2; ++s2)
      #pragma unroll
      for (int r = 0; r < 16; ++r)
        S[s2][r] = exp2f(S[s2][r] - m_i);

    // ---- pack P -> fp16 words; l-sum over the PACKED values ----
    unsigned pw[4][4];
    #pragma unroll
    for (int kc = 0; kc < 4; ++kc) {
      const int s2 = kc >> 1, a2 = kc & 1;
      pw[kc][0] = pkh(S[s2][8 * a2 + 0], S[s2][8 * a2 + 1]);
      pw[kc][1] = pkh(S[s2][8 * a2 + 2], S[s2][8 * a2 + 3]);
      pw[kc][2] = pkh(S[s2][8 * a2 + 4], S[s2][8 * a2 + 5]);
      pw[kc][3] = pkh(S[s2][8 * a2 + 6], S[s2][8 * a2 + 7]);
    }
    float rs = 0.f;
#if __has_builtin(__builtin_amdgcn_fdot2)
    {
      half2v one2;
      one2[0] = (_Float16)1.0f;
      one2[1] = (_Float16)1.0f;
      #pragma unroll
      for (int kc = 0; kc < 4; ++kc)
        #pragma unroll
        for (int u = 0; u < 4; ++u)
          rs = __builtin_amdgcn_fdot2(
              __builtin_bit_cast(half2v, pw[kc][u]), one2, rs, false);
    }
#else
    #pragma unroll
    for (int s2 = 0; s2 < 2; ++s2)
      #pragma unroll
      for (int r = 0; r < 16; ++r) rs += S[s2][r];
#endif
    rs += __shfl_xor(rs, 32, 64);
    l_i += rs;

    // ---- O^T += V^T . P^T ; P^T frags via permlane32_swap ----
    #pragma unroll
    for (int kc = 0; kc < 4; ++kc) {
      uint2v r0 = __builtin_amdgcn_permlane32_swap(pw[kc][0], pw[kc][2], false, false);
      uint2v r1 = __builtin_amdgcn_permlane32_swap(pw[kc][1], pw[kc][3], false, false);
      uint4v wv;
      wv.x = r0.x; wv.y = r1.x; wv.z = r0.y; wv.w = r1.y;
      half8 pfrag = __builtin_bit_cast(half8, wv);
      half8 va = lds_ld8(&Vt[lq * ST + kc * 16 + hh * 8]);
      half8 vb = lds_ld8(&Vt[(32 + lq) * ST + kc * 16 + hh * 8]);
      __builtin_amdgcn_s_setprio(1);
      O0 = MFMA32(va, pfrag, O0);
      O1 = MFMA32(vb, pfrag, O1);
      __builtin_amdgcn_s_setprio(0);
    }

    // ---- write next tile into the other buffer ----
    if (kt + 1 < 16) {
      _Float16* Kh2 = KhS[cur ^ 1];
      _Float16* Kl2 = KlS[cur ^ 1];
      _Float16* Vt2 = VtS[cur ^ 1];
      lds_st8(&Kh2[srow * ST + soff],     rkh0);
      lds_st8(&Kh2[srow * ST + soff + 8], rkh1);
      lds_st8(&Kl2[srow * ST + soff],     rkl0);
      lds_st8(&Kl2[srow * ST + soff + 8], rkl1);
      lds_st8(&Vt2[srow * ST + soff],     rv0);
      lds_st8(&Vt2[srow * ST + soff + 8], rv1);
    }
  }

  float inv = 1.0f / l_i;
  _Float16* orow = outa + ((size_t)b * L_ + q_row) * M_ + hd * 64;
  #pragma unroll
  for (int m = 0; m < 4; ++m) {
    half4 v0 = {(_Float16)(O0[4 * m + 0] * inv), (_Float16)(O0[4 * m + 1] * inv),
                (_Float16)(O0[4 * m + 2] * inv), (_Float16)(O0[4 * m + 3] * inv)};
    *(half4*)(orow + m * 8 + hh * 4) = v0;
    half4 v1 = {(_Float16)(O1[4 * m + 0] * inv), (_Float16)(O1[4 * m + 1] * inv),
                (_Float16)(O1[4 * m + 2] * inv), (_Float16)(O1[4 * m + 3] * inv)};
    *(half4*)(orow + 32 + m * 8 + hh * 4) = v1;
  }
}

// ---------------------------------------------------------------------------
// post_mfma: out(32768x512 f32) = attn_h(f16) x pwt(f16) + bias
// ---------------------------------------------------------------------------
__global__ __launch_bounds__(256, 2) void post_mfma(
    const _Float16* __restrict__ Ah, const _Float16* __restrict__ Wt,
    const float* __restrict__ bias, float* __restrict__ C)
{
  __shared__ _Float16 Ash[128 * 36];
  __shared__ _Float16 Bsh[128 * 36];

  const int t = threadIdx.x;
  const int lane = t & 63, w = t >> 6;
  const int wr = w >> 1, wc = w & 1;
  const int lr = lane & 31, hh = lane >> 5;
  const int col0 = blockIdx.x * 128;
  const int row0 = blockIdx.y * 128;

  const int sr = t >> 2;
  const int so = (t & 3) * 8;

  f32x16 acc[2][2];
  #pragma unroll
  for (int i = 0; i < 2; ++i)
    #pragma unroll
    for (int j = 0; j < 2; ++j)
      #pragma unroll
      for (int r = 0; r < 16; ++r) acc[i][j][r] = 0.f;

  half8 rah[2], rbh[2];
  #pragma unroll
  for (int i = 0; i < 2; ++i) {
    rah[i] = *(const half8*)(Ah + (size_t)(row0 + sr + i * 64) * M_ + so);
    rbh[i] = *(const half8*)(Wt + (size_t)(col0 + sr + i * 64) * M_ + so);
  }

  for (int k0 = 0; k0 < M_; k0 += 32) {
    #pragma unroll
    for (int i = 0; i < 2; ++i) {
      int r = sr + i * 64;
      lds_st8(&Ash[r * 36 + so], rah[i]);
      lds_st8(&Bsh[r * 36 + so], rbh[i]);
    }
    __syncthreads();
    if (k0 + 32 < M_) {
      #pragma unroll
      for (int i = 0; i < 2; ++i) {
        rah[i] = *(const half8*)(Ah + (size_t)(row0 + sr + i * 64) * M_ + k0 + 32 + so);
        rbh[i] = *(const half8*)(Wt + (size_t)(col0 + sr + i * 64) * M_ + k0 + 32 + so);
      }
    }
    half8 fah[2][2], fbh[2][2];
    #pragma unroll
    for (int c = 0; c < 2; ++c)
      #pragma unroll
      for (int i = 0; i < 2; ++i) {
        fah[c][i] = lds_ld8(&Ash[(wr * 64 + i * 32 + lr) * 36 + c * 16 + hh * 8]);
        fbh[c][i] = lds_ld8(&Bsh[(wc * 64 + i * 32 + lr) * 36 + c * 16 + hh * 8]);
      }
    __builtin_amdgcn_s_setprio(1);
    #pragma unroll
    for (int c = 0; c < 2; ++c)
      #pragma unroll
      for (int i = 0; i < 2; ++i)
        #pragma unroll
        for (int j = 0; j < 2; ++j)
          acc[i][j] = MFMA32(fah[c][i], fbh[c][j], acc[i][j]);
    __builtin_amdgcn_s_setprio(0);
    __syncthreads();
  }

  #pragma unroll
  for (int j = 0; j < 2; ++j) {
    const int cc = col0 + wc * 64 + j * 32 + lr;
    const float bs = bias[cc];
    #pragma unroll
    for (int i = 0; i < 2; ++i)
      #pragma unroll
      for (int r = 0; r < 16; ++r) {
        const int rrow = row0 + wr * 64 + i * 32 + (r & 3) + 8 * (r >> 2) + 4 * hh;
        C[(size_t)rrow * M_ + cc] = acc[i][j][r] + bs;
      }
  }
}

extern "C" void kernel_launch(void* const* d_in, const int* in_sizes, int n_in,
                              void* d_out, int out_size, void* d_ws, size_t ws_size,
                              hipStream_t stream) {
  const float* inp    = (const float*)d_in[0];
  const float* mask   = (const float*)d_in[1];
  const float* pre_w  = (const float*)d_in[2];
  const float* pre_b  = (const float*)d_in[3];
  const float* post_w = (const float*)d_in[4];
  const float* post_b = (const float*)d_in[5];
  float* out = (float*)d_out;

  const size_t HNE = (size_t)H_ * NR_ * D_;   // 16,777,216

  _Float16* w2t_hi = (_Float16*)d_ws;              // (1536,512)
  _Float16* w2t_lo = w2t_hi + (size_t)1536 * M_;
  _Float16* pwt    = w2t_lo + (size_t)1536 * M_;   // (512,512)
  _Float16* q_hi   = pwt + (size_t)M_ * M_;
  _Float16* q_lo   = q_hi + HNE;
  _Float16* k_hi   = q_lo + HNE;
  _Float16* k_lo   = k_hi + HNE;
  _Float16* v_t    = k_lo + HNE;              // (8,32,64,1024) transposed v
  _Float16* mask2  = v_t + HNE;               // (1024,1024) fp16
  _Float16* attn_h = mask2 + (size_t)L_ * L_; // (32768,512) fp16

  prep<<<1024, 256, 0, stream>>>(pre_w, w2t_hi, w2t_lo, post_w, pwt, mask, mask2);

  qkv_fused<<<dim3(12, 256), 512, 0, stream>>>(
      inp, w2t_hi, w2t_lo, pre_b, q_hi, q_lo, k_hi, k_lo, v_t);

  attn_mfma<<<dim3(256, 8), 256, 0, stream>>>(q_hi, q_lo, k_hi, k_lo, v_t,
                                              mask2, attn_h);

  post_mfma<<<dim3(4, 256), 256, 0, stream>>>(attn_h, pwt, post_b, out);
}

// Round 16
// 457.236 us; speedup vs baseline: 1.1545x; 1.0060x over previous
//
#include <hip/hip_runtime.h>

#define H_ 8
#define B_ 32
#define L_ 1024
#define D_ 64
#define M_ 512
#define NR_ 32768  // B_*L_
#define LOG2E 1.44269504088896340736f

typedef _Float16 half8 __attribute__((ext_vector_type(8)));
typedef _Float16 half4 __attribute__((ext_vector_type(4)));
typedef _Float16 half2v __attribute__((ext_vector_type(2)));
typedef float f32x16 __attribute__((ext_vector_type(16)));
typedef unsigned int uint2v __attribute__((ext_vector_type(2)));
typedef unsigned int uint4v __attribute__((ext_vector_type(4)));

#define MFMA32(A, B, C) __builtin_amdgcn_mfma_f32_32x32x16_f16(A, B, C, 0, 0, 0)

static __device__ __forceinline__ unsigned pkh(float a, float b) {
  return __builtin_bit_cast(unsigned, __builtin_amdgcn_cvt_pkrtz(a, b));
}
// 8B-aligned LDS moves (row strides 36/68 halves are 8B- but not 16B-aligned)
static __device__ __forceinline__ half8 lds_ld8(const _Float16* p) {
  half4 a = *(const half4*)p;
  half4 b = *(const half4*)(p + 4);
  return __builtin_shufflevector(a, b, 0, 1, 2, 3, 4, 5, 6, 7);
}
static __device__ __forceinline__ void lds_st8(_Float16* p, half8 v) {
  *(half4*)p       = __builtin_shufflevector(v, v, 0, 1, 2, 3);
  *(half4*)(p + 4) = __builtin_shufflevector(v, v, 4, 5, 6, 7);
}
struct half2s { _Float16 h, l; };
static __device__ __forceinline__ half2s split1(float x) {
  half2s r;
  r.h = (_Float16)x;
  r.l = (_Float16)(x - (float)r.h);
  return r;
}

// ---------------------------------------------------------------------------
// prep: three small jobs in one launch.  mask2 is f32 * log2(e)  (no cvt in
// the attn hot loop; the fp16-mask experiment showed footprint isn't binding).
// ---------------------------------------------------------------------------
__global__ __launch_bounds__(256) void prep(
    const float* __restrict__ pre_w, _Float16* __restrict__ w2t_hi,
    _Float16* __restrict__ w2t_lo,
    const float* __restrict__ post_w, _Float16* __restrict__ pwt,
    const float* __restrict__ mask, float* __restrict__ mask2)
{
  const int bid = blockIdx.x;
  const int t = threadIdx.x;
  if (bid < 384) {
    const int gid = bid * 256 + t;
    const int cc = gid >> 6;
    const int m0 = (gid & 63) << 3;
    const int g = cc >> 6, d = cc & 63;
    half8 h, l;
    #pragma unroll
    for (int j = 0; j < 8; ++j) {
      half2s s = split1(pre_w[((size_t)g * M_ + m0 + j) * D_ + d]);
      h[j] = s.h;
      l[j] = s.l;
    }
    *(half8*)(w2t_hi + (size_t)cc * M_ + m0) = h;
    *(half8*)(w2t_lo + (size_t)cc * M_ + m0) = l;
  } else if (bid < 512) {
    const int gid = (bid - 384) * 256 + t;
    const int cc = gid >> 6;
    const int m0 = (gid & 63) << 3;
    half8 h;
    #pragma unroll
    for (int j = 0; j < 8; ++j) h[j] = (_Float16)post_w[(size_t)(m0 + j) * M_ + cc];
    *(half8*)(pwt + (size_t)cc * M_ + m0) = h;
  } else {
    const size_t i = (size_t)(bid - 512) * 256 + t;  // per float4
    float4 v = ((const float4*)mask)[i * 2];
    float4 u = ((const float4*)mask)[i * 2 + 1];
    float4 rv = {v.x * LOG2E, v.y * LOG2E, v.z * LOG2E, v.w * LOG2E};
    float4 ru = {u.x * LOG2E, u.y * LOG2E, u.z * LOG2E, u.w * LOG2E};
    ((float4*)mask2)[i * 2]     = rv;
    ((float4*)mask2)[i * 2 + 1] = ru;
  }
}

// ---------------------------------------------------------------------------
// qkv_fused v5 (frozen): 512-thread / 8-wave, coalesced stage->LDS, 64x32
// wave tiles. Blocks 0..7 (q,k): 3-term hi/lo. Blocks 8..11 (v): 1-term.
// ---------------------------------------------------------------------------
__global__ __launch_bounds__(512, 4) void qkv_fused(
    const float* __restrict__ A,
    const _Float16* __restrict__ Whi, const _Float16* __restrict__ Wlo,
    const float* __restrict__ bias,
    _Float16* __restrict__ qh, _Float16* __restrict__ ql,
    _Float16* __restrict__ kh, _Float16* __restrict__ kl,
    _Float16* __restrict__ vt)
{
  __shared__ _Float16 Ash[128 * 36];
  __shared__ _Float16 Asl[128 * 36];
  __shared__ _Float16 Bsh[128 * 36];
  __shared__ _Float16 Bsl[128 * 36];   // 36864 B

  const bool THREE = blockIdx.x < 8;
  const int t = threadIdx.x;            // 0..511
  const int lane = t & 63, w = t >> 6;  // 8 waves
  const int wr = w >> 2, wc = w & 3;    // 2 x 4 wave grid
  const int lr = lane & 31, hh = lane >> 5;
  const int col0 = blockIdx.x * 128;
  const int row0 = blockIdx.y * 128;

  const int sr = t >> 2;          // 0..127
  const int so = (t & 3) * 8;     // 0,8,16,24

  const float*    Ab  = &A  [(size_t)(row0 + sr) * M_ + so];
  const _Float16* Wb  = &Whi[(size_t)(col0 + sr) * M_ + so];
  const _Float16* Wlb = &Wlo[(size_t)(col0 + sr) * M_ + so];

  f32x16 acc[2];
  #pragma unroll
  for (int i = 0; i < 2; ++i)
    #pragma unroll
    for (int r = 0; r < 16; ++r) acc[i][r] = 0.f;

  // initial prefetch (k-slab 0)
  float4 ra0 = *(const float4*)Ab;
  float4 ra1 = *(const float4*)(Ab + 4);
  half8 rbh = *(const half8*)Wb;
  half8 rbl;
  if (THREE) rbl = *(const half8*)Wlb;

  for (int k0 = 0; k0 < M_; k0 += 32) {
    // convert + store staged regs into LDS
    {
      float v[8] = {ra0.x, ra0.y, ra0.z, ra0.w, ra1.x, ra1.y, ra1.z, ra1.w};
      half8 h, l;
      if (THREE) {
        #pragma unroll
        for (int j = 0; j < 8; ++j) { half2s s = split1(v[j]); h[j] = s.h; l[j] = s.l; }
        lds_st8(&Asl[sr * 36 + so], l);
        lds_st8(&Bsl[sr * 36 + so], rbl);
      } else {
        #pragma unroll
        for (int j = 0; j < 8; ++j) h[j] = (_Float16)v[j];
      }
      lds_st8(&Ash[sr * 36 + so], h);
      lds_st8(&Bsh[sr * 36 + so], rbh);
    }
    __syncthreads();
    if (k0 + 32 < M_) {
      ra0 = *(const float4*)(Ab + k0 + 32);
      ra1 = *(const float4*)(Ab + k0 + 36);
      rbh = *(const half8*)(Wb + k0 + 32);
      if (THREE) rbl = *(const half8*)(Wlb + k0 + 32);
    }

    // fragments: A rows (wr*64 + i*32 + lr), W col (wc*32 + lr)
    half8 fah[2][2], fal[2][2], fbh[2], fbl[2];   // [c][i] / [c]
    #pragma unroll
    for (int c = 0; c < 2; ++c) {
      #pragma unroll
      for (int i = 0; i < 2; ++i) {
        const int ar = (wr * 64 + i * 32 + lr) * 36 + c * 16 + hh * 8;
        fah[c][i] = lds_ld8(&Ash[ar]);
        if (THREE) fal[c][i] = lds_ld8(&Asl[ar]);
      }
      const int br = (wc * 32 + lr) * 36 + c * 16 + hh * 8;
      fbh[c] = lds_ld8(&Bsh[br]);
      if (THREE) fbl[c] = lds_ld8(&Bsl[br]);
    }

    __builtin_amdgcn_s_setprio(1);
    #pragma unroll
    for (int c = 0; c < 2; ++c) {
      #pragma unroll
      for (int i = 0; i < 2; ++i)
        acc[i] = MFMA32(fah[c][i], fbh[c], acc[i]);
      if (THREE) {
        #pragma unroll
        for (int i = 0; i < 2; ++i)
          acc[i] = MFMA32(fah[c][i], fbl[c], acc[i]);
        #pragma unroll
        for (int i = 0; i < 2; ++i)
          acc[i] = MFMA32(fal[c][i], fbh[c], acc[i]);
      }
    }
    __builtin_amdgcn_s_setprio(0);
    __syncthreads();
  }

  // epilogue: wave covers rows [row0+wr*64, +64), cols [col0+wc*32, +32)
  {
    const int cc = col0 + wc * 32 + lr;
    const int g = cc >> 6;
    const int t3 = g >> 3, hd = g & 7;
    const int d = cc & 63;
    const float bs = bias[cc];
    #pragma unroll
    for (int i = 0; i < 2; ++i) {
      if (THREE) {
        #pragma unroll
        for (int r = 0; r < 16; ++r) {
          const int rrow = row0 + wr * 64 + i * 32 + (r & 3) + 8 * (r >> 2) + 4 * hh;
          const float x = acc[i][r] + bs;
          const size_t base = ((size_t)hd * NR_ + rrow) * D_ + d;
          if (t3 == 0) {
            half2s s = split1(x * LOG2E);   // fold log2(e) into Q
            qh[base] = s.h; ql[base] = s.l;
          } else {
            half2s s = split1(x);
            kh[base] = s.h; kl[base] = s.l;
          }
        }
      } else {
        // v: transposed layout, half4 stores along l (consecutive r&3)
        #pragma unroll
        for (int m = 0; m < 4; ++m) {
          const int rbase = row0 + wr * 64 + i * 32 + 8 * m + 4 * hh;
          const int bb = rbase >> 10;
          const int ll = rbase & 1023;
          half4 v4;
          #pragma unroll
          for (int u = 0; u < 4; ++u) v4[u] = (_Float16)(acc[i][4 * m + u] + bs);
          *(half4*)(vt + (((size_t)hd * 32 + bb) * 64 + d) * 1024 + ll) = v4;
        }
      }
    }
  }
}

// ---------------------------------------------------------------------------
// attn_mfma v10: VALU diet on the v9 structure.
// - f32 mask (no 32 cvt/kt; C-init direct); phase-major grid kept
// - defer-max THR=12 (P <= 2^12, fp16-safe; rescale fires ~2.5/16 kt)
// - l-sum fdot2 in 4 parallel chains (dep depth 16 -> 4)
// ---------------------------------------------------------------------------
__global__ __launch_bounds__(256, 3) void attn_mfma(
    const _Float16* __restrict__ qh, const _Float16* __restrict__ ql,
    const _Float16* __restrict__ kh, const _Float16* __restrict__ kl,
    const _Float16* __restrict__ vt,  // (8,32,64,1024) halves: [hd][b][d][l]
    const float* __restrict__ mask2,  // (1024,1024) f32, pre-scaled log2(e)
    _Float16* __restrict__ outa)      // (32768, 512) fp16
{
  constexpr int ST = 68;              // halves; 8B-aligned rows
  __shared__ _Float16 KhS[2][64 * ST];
  __shared__ _Float16 KlS[2][64 * ST];
  __shared__ _Float16 VtS[2][64 * ST];   // [d][k] row-major

  const int t    = threadIdx.x;
  const int lane = t & 63, w = t >> 6;
  const int lq   = lane & 31, hh = lane >> 5;
  const int qt = blockIdx.y;          // 0..7  (phase-major dispatch)
  const int bh = blockIdx.x;          // 0..255
  const int b  = bh & 31;
  const int hd = bh >> 5;

  const int q_row = qt * 128 + w * 32 + lq;
  const size_t headoff = (size_t)hd * NR_ * D_ + (size_t)b * L_ * D_;

  const size_t qbase = headoff + (size_t)q_row * D_;
  half8 Qhc[4], Qlc[4];
  #pragma unroll
  for (int c = 0; c < 4; ++c) {
    Qhc[c] = *(const half8*)(qh + qbase + c * 16 + hh * 8);
    Qlc[c] = *(const half8*)(ql + qbase + c * 16 + hh * 8);
  }

  const _Float16* Kph = kh + headoff;
  const _Float16* Kpl = kl + headoff;
  const _Float16* Vtp = vt + ((size_t)hd * 32 + b) * (64 * 1024);  // [d][l]
  const float*   mrow = mask2 + (size_t)q_row * L_;

  const int srow = t >> 2;            // 0..63
  const int soff = (t & 3) * 16;      // 0,16,32,48 halves

  float m_i = -3.0e38f, l_i = 0.f;
  f32x16 O0, O1;
  #pragma unroll
  for (int i = 0; i < 16; ++i) { O0[i] = 0.f; O1[i] = 0.f; }

  // staging registers (next K/V tile in flight)
  half8 rkh0, rkh1, rkl0, rkl1, rv0, rv1;
  {
    const size_t goff  = (size_t)srow * D_ + soff;        // K tile kt=0
    const size_t goffv = (size_t)srow * 1024 + soff;      // V^T tile kt=0
    rkh0 = *(const half8*)(Kph + goff);
    rkh1 = *(const half8*)(Kph + goff + 8);
    rkl0 = *(const half8*)(Kpl + goff);
    rkl1 = *(const half8*)(Kpl + goff + 8);
    rv0  = *(const half8*)(Vtp + goffv);
    rv1  = *(const half8*)(Vtp + goffv + 8);
  }
  {
    lds_st8(&KhS[0][srow * ST + soff],     rkh0);
    lds_st8(&KhS[0][srow * ST + soff + 8], rkh1);
    lds_st8(&KlS[0][srow * ST + soff],     rkl0);
    lds_st8(&KlS[0][srow * ST + soff + 8], rkl1);
    lds_st8(&VtS[0][srow * ST + soff],     rv0);
    lds_st8(&VtS[0][srow * ST + soff + 8], rv1);
  }

  for (int kt = 0; kt < 16; ++kt) {
    const int cur = kt & 1;

    // mask loads for this kt (f32, issued BEFORE the barrier; C-init use)
    float4 mc[8];
    #pragma unroll
    for (int m = 0; m < 8; ++m)
      mc[m] = *(const float4*)(mrow + kt * 64 + (m >> 2) * 32 + (m & 3) * 8 + hh * 4);

    __syncthreads();   // buf[cur] complete

    // issue next-tile global loads (consumed at end-of-iter LDS write)
    if (kt + 1 < 16) {
      const size_t goff  = (size_t)((kt + 1) * 64 + srow) * D_ + soff;
      const size_t goffv = (size_t)srow * 1024 + (kt + 1) * 64 + soff;
      rkh0 = *(const half8*)(Kph + goff);
      rkh1 = *(const half8*)(Kph + goff + 8);
      rkl0 = *(const half8*)(Kpl + goff);
      rkl1 = *(const half8*)(Kpl + goff + 8);
      rv0  = *(const half8*)(Vtp + goffv);
      rv1  = *(const half8*)(Vtp + goffv + 8);
    }

    const _Float16* Kh = KhS[cur];
    const _Float16* Kl = KlS[cur];
    const _Float16* Vt = VtS[cur];

    // ---- S^T = K . Q + mask (mask in the MFMA C-init, no conversion) ----
    f32x16 S[2];
    #pragma unroll
    for (int s2 = 0; s2 < 2; ++s2) {
      f32x16 acc;
      #pragma unroll
      for (int m = 0; m < 4; ++m) {
        float4 mv = mc[s2 * 4 + m];
        acc[4 * m + 0] = mv.x;
        acc[4 * m + 1] = mv.y;
        acc[4 * m + 2] = mv.z;
        acc[4 * m + 3] = mv.w;
      }
      #pragma unroll
      for (int c = 0; c < 4; ++c) {
        half8 ah = lds_ld8(&Kh[(s2 * 32 + lq) * ST + c * 16 + hh * 8]);
        half8 al = lds_ld8(&Kl[(s2 * 32 + lq) * ST + c * 16 + hh * 8]);
        __builtin_amdgcn_s_setprio(1);
        acc = MFMA32(ah, Qhc[c], acc);
        acc = MFMA32(ah, Qlc[c], acc);
        acc = MFMA32(al, Qhc[c], acc);
        __builtin_amdgcn_s_setprio(0);
      }
      S[s2] = acc;
    }

    // ---- tile max (max3-friendly tree) ----
    float pm[8];
    #pragma unroll
    for (int g4 = 0; g4 < 8; ++g4) {
      const int s2 = g4 >> 2, m = g4 & 3;
      pm[g4] = fmaxf(fmaxf(S[s2][4 * m + 0], S[s2][4 * m + 1]),
                     fmaxf(S[s2][4 * m + 2], S[s2][4 * m + 3]));
    }
    float tmax = fmaxf(fmaxf(fmaxf(pm[0], pm[1]), fmaxf(pm[2], pm[3])),
                       fmaxf(fmaxf(pm[4], pm[5]), fmaxf(pm[6], pm[7])));
    tmax = fmaxf(tmax, __shfl_xor(tmax, 32, 64));

    // ---- defer-max: rescale only when tile max grows past m_i + 12 ----
    if (!__all(tmax - m_i <= 12.0f)) {
      float mn = fmaxf(m_i, tmax);
      float sc = exp2f(m_i - mn);
      m_i = mn;
      l_i *= sc;
      O0 = O0 * sc;
      O1 = O1 * sc;
    }

    #pragma unroll
    for (int s2 = 0; s2 < 2; ++s2)
      #pragma unroll
      for (int r = 0; r < 16; ++r)
        S[s2][r] = exp2f(S[s2][r] - m_i);

    // ---- pack P -> fp16 words; l-sum over packed values (4 chains) ----
    unsigned pw[4][4];
    #pragma unroll
    for (int kc = 0; kc < 4; ++kc) {
      const int s2 = kc >> 1, a2 = kc & 1;
      pw[kc][0] = pkh(S[s2][8 * a2 + 0], S[s2][8 * a2 + 1]);
      pw[kc][1] = pkh(S[s2][8 * a2 + 2], S[s2][8 * a2 + 3]);
      pw[kc][2] = pkh(S[s2][8 * a2 + 4], S[s2][8 * a2 + 5]);
      pw[kc][3] = pkh(S[s2][8 * a2 + 6], S[s2][8 * a2 + 7]);
    }
    float rs;
#if __has_builtin(__builtin_amdgcn_fdot2)
    {
      half2v one2;
      one2[0] = (_Float16)1.0f;
      one2[1] = (_Float16)1.0f;
      float c0 = 0.f, c1 = 0.f, c2 = 0.f, c3 = 0.f;
      #pragma unroll
      for (int kc = 0; kc < 4; ++kc) {
        c0 = __builtin_amdgcn_fdot2(__builtin_bit_cast(half2v, pw[kc][0]), one2, c0, false);
        c1 = __builtin_amdgcn_fdot2(__builtin_bit_cast(half2v, pw[kc][1]), one2, c1, false);
        c2 = __builtin_amdgcn_fdot2(__builtin_bit_cast(half2v, pw[kc][2]), one2, c2, false);
        c3 = __builtin_amdgcn_fdot2(__builtin_bit_cast(half2v, pw[kc][3]), one2, c3, false);
      }
      rs = (c0 + c1) + (c2 + c3);
    }
#else
    rs = 0.f;
    #pragma unroll
    for (int s2 = 0; s2 < 2; ++s2)
      #pragma unroll
      for (int r = 0; r < 16; ++r) rs += S[s2][r];
#endif
    rs += __shfl_xor(rs, 32, 64);
    l_i += rs;

    // ---- O^T += V^T . P^T ; P^T frags via permlane32_swap ----
    #pragma unroll
    for (int kc = 0; kc < 4; ++kc) {
      uint2v r0 = __builtin_amdgcn_permlane32_swap(pw[kc][0], pw[kc][2], false, false);
      uint2v r1 = __builtin_amdgcn_permlane32_swap(pw[kc][1], pw[kc][3], false, false);
      uint4v wv;
      wv.x = r0.x; wv.y = r1.x; wv.z = r0.y; wv.w = r1.y;
      half8 pfrag = __builtin_bit_cast(half8, wv);
      half8 va = lds_ld8(&Vt[lq * ST + kc * 16 + hh * 8]);
      half8 vb = lds_ld8(&Vt[(32 + lq) * ST + kc * 16 + hh * 8]);
      __builtin_amdgcn_s_setprio(1);
      O0 = MFMA32(va, pfrag, O0);
      O1 = MFMA32(vb, pfrag, O1);
      __builtin_amdgcn_s_setprio(0);
    }

    // ---- write next tile into the other buffer ----
    if (kt + 1 < 16) {
      _Float16* Kh2 = KhS[cur ^ 1];
      _Float16* Kl2 = KlS[cur ^ 1];
      _Float16* Vt2 = VtS[cur ^ 1];
      lds_st8(&Kh2[srow * ST + soff],     rkh0);
      lds_st8(&Kh2[srow * ST + soff + 8], rkh1);
      lds_st8(&Kl2[srow * ST + soff],     rkl0);
      lds_st8(&Kl2[srow * ST + soff + 8], rkl1);
      lds_st8(&Vt2[srow * ST + soff],     rv0);
      lds_st8(&Vt2[srow * ST + soff + 8], rv1);
    }
  }

  float inv = 1.0f / l_i;
  _Float16* orow = outa + ((size_t)b * L_ + q_row) * M_ + hd * 64;
  #pragma unroll
  for (int m = 0; m < 4; ++m) {
    half4 v0 = {(_Float16)(O0[4 * m + 0] * inv), (_Float16)(O0[4 * m + 1] * inv),
                (_Float16)(O0[4 * m + 2] * inv), (_Float16)(O0[4 * m + 3] * inv)};
    *(half4*)(orow + m * 8 + hh * 4) = v0;
    half4 v1 = {(_Float16)(O1[4 * m + 0] * inv), (_Float16)(O1[4 * m + 1] * inv),
                (_Float16)(O1[4 * m + 2] * inv), (_Float16)(O1[4 * m + 3] * inv)};
    *(half4*)(orow + 32 + m * 8 + hh * 4) = v1;
  }
}

// ---------------------------------------------------------------------------
// post_mfma (frozen): out(32768x512 f32) = attn_h(f16) x pwt(f16) + bias
// ---------------------------------------------------------------------------
__global__ __launch_bounds__(256, 2) void post_mfma(
    const _Float16* __restrict__ Ah, const _Float16* __restrict__ Wt,
    const float* __restrict__ bias, float* __restrict__ C)
{
  __shared__ _Float16 Ash[128 * 36];
  __shared__ _Float16 Bsh[128 * 36];

  const int t = threadIdx.x;
  const int lane = t & 63, w = t >> 6;
  const int wr = w >> 1, wc = w & 1;
  const int lr = lane & 31, hh = lane >> 5;
  const int col0 = blockIdx.x * 128;
  const int row0 = blockIdx.y * 128;

  const int sr = t >> 2;
  const int so = (t & 3) * 8;

  f32x16 acc[2][2];
  #pragma unroll
  for (int i = 0; i < 2; ++i)
    #pragma unroll
    for (int j = 0; j < 2; ++j)
      #pragma unroll
      for (int r = 0; r < 16; ++r) acc[i][j][r] = 0.f;

  half8 rah[2], rbh[2];
  #pragma unroll
  for (int i = 0; i < 2; ++i) {
    rah[i] = *(const half8*)(Ah + (size_t)(row0 + sr + i * 64) * M_ + so);
    rbh[i] = *(const half8*)(Wt + (size_t)(col0 + sr + i * 64) * M_ + so);
  }

  for (int k0 = 0; k0 < M_; k0 += 32) {
    #pragma unroll
    for (int i = 0; i < 2; ++i) {
      int r = sr + i * 64;
      lds_st8(&Ash[r * 36 + so], rah[i]);
      lds_st8(&Bsh[r * 36 + so], rbh[i]);
    }
    __syncthreads();
    if (k0 + 32 < M_) {
      #pragma unroll
      for (int i = 0; i < 2; ++i) {
        rah[i] = *(const half8*)(Ah + (size_t)(row0 + sr + i * 64) * M_ + k0 + 32 + so);
        rbh[i] = *(const half8*)(Wt + (size_t)(col0 + sr + i * 64) * M_ + k0 + 32 + so);
      }
    }
    half8 fah[2][2], fbh[2][2];
    #pragma unroll
    for (int c = 0; c < 2; ++c)
      #pragma unroll
      for (int i = 0; i < 2; ++i) {
        fah[c][i] = lds_ld8(&Ash[(wr * 64 + i * 32 + lr) * 36 + c * 16 + hh * 8]);
        fbh[c][i] = lds_ld8(&Bsh[(wc * 64 + i * 32 + lr) * 36 + c * 16 + hh * 8]);
      }
    __builtin_amdgcn_s_setprio(1);
    #pragma unroll
    for (int c = 0; c < 2; ++c)
      #pragma unroll
      for (int i = 0; i < 2; ++i)
        #pragma unroll
        for (int j = 0; j < 2; ++j)
          acc[i][j] = MFMA32(fah[c][i], fbh[c][j], acc[i][j]);
    __builtin_amdgcn_s_setprio(0);
    __syncthreads();
  }

  #pragma unroll
  for (int j = 0; j < 2; ++j) {
    const int cc = col0 + wc * 64 + j * 32 + lr;
    const float bs = bias[cc];
    #pragma unroll
    for (int i = 0; i < 2; ++i)
      #pragma unroll
      for (int r = 0; r < 16; ++r) {
        const int rrow = row0 + wr * 64 + i * 32 + (r & 3) + 8 * (r >> 2) + 4 * hh;
        C[(size_t)rrow * M_ + cc] = acc[i][j][r] + bs;
      }
  }
}

extern "C" void kernel_launch(void* const* d_in, const int* in_sizes, int n_in,
                              void* d_out, int out_size, void* d_ws, size_t ws_size,
                              hipStream_t stream) {
  const float* inp    = (const float*)d_in[0];
  const float* mask   = (const float*)d_in[1];
  const float* pre_w  = (const float*)d_in[2];
  const float* pre_b  = (const float*)d_in[3];
  const float* post_w = (const float*)d_in[4];
  const float* post_b = (const float*)d_in[5];
  float* out = (float*)d_out;

  const size_t HNE = (size_t)H_ * NR_ * D_;   // 16,777,216

  _Float16* w2t_hi = (_Float16*)d_ws;              // (1536,512)
  _Float16* w2t_lo = w2t_hi + (size_t)1536 * M_;
  _Float16* pwt    = w2t_lo + (size_t)1536 * M_;   // (512,512)
  _Float16* q_hi   = pwt + (size_t)M_ * M_;
  _Float16* q_lo   = q_hi + HNE;
  _Float16* k_hi   = q_lo + HNE;
  _Float16* k_lo   = k_hi + HNE;
  _Float16* v_t    = k_lo + HNE;              // (8,32,64,1024) transposed v
  float*    mask2  = (float*)(v_t + HNE);     // (1024,1024) f32
  _Float16* attn_h = (_Float16*)(mask2 + (size_t)L_ * L_);  // (32768,512) fp16

  prep<<<1024, 256, 0, stream>>>(pre_w, w2t_hi, w2t_lo, post_w, pwt, mask, mask2);

  qkv_fused<<<dim3(12, 256), 512, 0, stream>>>(
      inp, w2t_hi, w2t_lo, pre_b, q_hi, q_lo, k_hi, k_lo, v_t);

  attn_mfma<<<dim3(256, 8), 256, 0, stream>>>(q_hi, q_lo, k_hi, k_lo, v_t,
                                              mask2, attn_h);

  post_mfma<<<dim3(4, 256), 256, 0, stream>>>(attn_h, pwt, post_b, out);
}

// Round 17
// 440.423 us; speedup vs baseline: 1.1985x; 1.0382x over previous
//
#include <hip/hip_runtime.h>

#define H_ 8
#define B_ 32
#define L_ 1024
#define D_ 64
#define M_ 512
#define NR_ 32768  // B_*L_
#define LOG2E 1.44269504088896340736f

typedef _Float16 half8 __attribute__((ext_vector_type(8)));
typedef _Float16 half4 __attribute__((ext_vector_type(4)));
typedef _Float16 half2v __attribute__((ext_vector_type(2)));
typedef float f32x16 __attribute__((ext_vector_type(16)));
typedef unsigned int uint2v __attribute__((ext_vector_type(2)));
typedef unsigned int uint4v __attribute__((ext_vector_type(4)));

#define MFMA32(A, B, C) __builtin_amdgcn_mfma_f32_32x32x16_f16(A, B, C, 0, 0, 0)

static __device__ __forceinline__ unsigned pkh(float a, float b) {
  return __builtin_bit_cast(unsigned, __builtin_amdgcn_cvt_pkrtz(a, b));
}
// 8B-aligned LDS moves (row strides 36/68 halves are 8B- but not 16B-aligned)
static __device__ __forceinline__ half8 lds_ld8(const _Float16* p) {
  half4 a = *(const half4*)p;
  half4 b = *(const half4*)(p + 4);
  return __builtin_shufflevector(a, b, 0, 1, 2, 3, 4, 5, 6, 7);
}
static __device__ __forceinline__ void lds_st8(_Float16* p, half8 v) {
  *(half4*)p       = __builtin_shufflevector(v, v, 0, 1, 2, 3);
  *(half4*)(p + 4) = __builtin_shufflevector(v, v, 4, 5, 6, 7);
}
struct half2s { _Float16 h, l; };
static __device__ __forceinline__ half2s split1(float x) {
  half2s r;
  r.h = (_Float16)x;
  r.l = (_Float16)(x - (float)r.h);
  return r;
}

// ---------------------------------------------------------------------------
// prep: three small jobs in one launch (mask -> fp16 * log2(e)).
// ---------------------------------------------------------------------------
__global__ __launch_bounds__(256) void prep(
    const float* __restrict__ pre_w, _Float16* __restrict__ w2t_hi,
    _Float16* __restrict__ w2t_lo,
    const float* __restrict__ post_w, _Float16* __restrict__ pwt,
    const float* __restrict__ mask, _Float16* __restrict__ mask2)
{
  const int bid = blockIdx.x;
  const int t = threadIdx.x;
  if (bid < 384) {
    const int gid = bid * 256 + t;
    const int cc = gid >> 6;
    const int m0 = (gid & 63) << 3;
    const int g = cc >> 6, d = cc & 63;
    half8 h, l;
    #pragma unroll
    for (int j = 0; j < 8; ++j) {
      half2s s = split1(pre_w[((size_t)g * M_ + m0 + j) * D_ + d]);
      h[j] = s.h;
      l[j] = s.l;
    }
    *(half8*)(w2t_hi + (size_t)cc * M_ + m0) = h;
    *(half8*)(w2t_lo + (size_t)cc * M_ + m0) = l;
  } else if (bid < 512) {
    const int gid = (bid - 384) * 256 + t;
    const int cc = gid >> 6;
    const int m0 = (gid & 63) << 3;
    half8 h;
    #pragma unroll
    for (int j = 0; j < 8; ++j) h[j] = (_Float16)post_w[(size_t)(m0 + j) * M_ + cc];
    *(half8*)(pwt + (size_t)cc * M_ + m0) = h;
  } else {
    const size_t i = (size_t)(bid - 512) * 256 + t;  // per 8 elems
    float4 a = ((const float4*)mask)[i * 2];
    float4 b = ((const float4*)mask)[i * 2 + 1];
    float v[8] = {a.x, a.y, a.z, a.w, b.x, b.y, b.z, b.w};
    half8 h;
    #pragma unroll
    for (int j = 0; j < 8; ++j) h[j] = (_Float16)(v[j] * LOG2E);
    *(half8*)(mask2 + i * 8) = h;
  }
}

// ---------------------------------------------------------------------------
// qkv_fused v6: v5 structure + XCD-contiguous block swizzle.
// 1-D grid 3072; dispatch round-robins id%8 across XCDs, so
// swz = (id&7)*384 + (id>>3) gives each XCD 32 contiguous row-blocks:
// all 12 col-blocks sharing one 256 KB A-slab hit ONE XCD's L2, and that
// XCD's 12 W panels (3 MB hi+lo) also stay L2-resident.
// ---------------------------------------------------------------------------
__global__ __launch_bounds__(512, 4) void qkv_fused(
    const float* __restrict__ A,
    const _Float16* __restrict__ Whi, const _Float16* __restrict__ Wlo,
    const float* __restrict__ bias,
    _Float16* __restrict__ qh, _Float16* __restrict__ ql,
    _Float16* __restrict__ kh, _Float16* __restrict__ kl,
    _Float16* __restrict__ vt)
{
  __shared__ _Float16 Ash[128 * 36];
  __shared__ _Float16 Asl[128 * 36];
  __shared__ _Float16 Bsh[128 * 36];
  __shared__ _Float16 Bsl[128 * 36];   // 36864 B

  const int id  = blockIdx.x;                  // 0..3071
  const int swz = (id & 7) * 384 + (id >> 3);  // bijective XCD-chunking
  const int cb  = swz % 12;
  const int rb  = swz / 12;

  const bool THREE = cb < 8;
  const int t = threadIdx.x;            // 0..511
  const int lane = t & 63, w = t >> 6;  // 8 waves
  const int wr = w >> 2, wc = w & 3;    // 2 x 4 wave grid
  const int lr = lane & 31, hh = lane >> 5;
  const int col0 = cb * 128;
  const int row0 = rb * 128;

  const int sr = t >> 2;          // 0..127
  const int so = (t & 3) * 8;     // 0,8,16,24

  const float*    Ab  = &A  [(size_t)(row0 + sr) * M_ + so];
  const _Float16* Wb  = &Whi[(size_t)(col0 + sr) * M_ + so];
  const _Float16* Wlb = &Wlo[(size_t)(col0 + sr) * M_ + so];

  f32x16 acc[2];
  #pragma unroll
  for (int i = 0; i < 2; ++i)
    #pragma unroll
    for (int r = 0; r < 16; ++r) acc[i][r] = 0.f;

  // initial prefetch (k-slab 0)
  float4 ra0 = *(const float4*)Ab;
  float4 ra1 = *(const float4*)(Ab + 4);
  half8 rbh = *(const half8*)Wb;
  half8 rbl;
  if (THREE) rbl = *(const half8*)Wlb;

  for (int k0 = 0; k0 < M_; k0 += 32) {
    // convert + store staged regs into LDS
    {
      float v[8] = {ra0.x, ra0.y, ra0.z, ra0.w, ra1.x, ra1.y, ra1.z, ra1.w};
      half8 h, l;
      if (THREE) {
        #pragma unroll
        for (int j = 0; j < 8; ++j) { half2s s = split1(v[j]); h[j] = s.h; l[j] = s.l; }
        lds_st8(&Asl[sr * 36 + so], l);
        lds_st8(&Bsl[sr * 36 + so], rbl);
      } else {
        #pragma unroll
        for (int j = 0; j < 8; ++j) h[j] = (_Float16)v[j];
      }
      lds_st8(&Ash[sr * 36 + so], h);
      lds_st8(&Bsh[sr * 36 + so], rbh);
    }
    __syncthreads();
    if (k0 + 32 < M_) {
      ra0 = *(const float4*)(Ab + k0 + 32);
      ra1 = *(const float4*)(Ab + k0 + 36);
      rbh = *(const half8*)(Wb + k0 + 32);
      if (THREE) rbl = *(const half8*)(Wlb + k0 + 32);
    }

    // fragments: A rows (wr*64 + i*32 + lr), W col (wc*32 + lr)
    half8 fah[2][2], fal[2][2], fbh[2], fbl[2];   // [c][i] / [c]
    #pragma unroll
    for (int c = 0; c < 2; ++c) {
      #pragma unroll
      for (int i = 0; i < 2; ++i) {
        const int ar = (wr * 64 + i * 32 + lr) * 36 + c * 16 + hh * 8;
        fah[c][i] = lds_ld8(&Ash[ar]);
        if (THREE) fal[c][i] = lds_ld8(&Asl[ar]);
      }
      const int br = (wc * 32 + lr) * 36 + c * 16 + hh * 8;
      fbh[c] = lds_ld8(&Bsh[br]);
      if (THREE) fbl[c] = lds_ld8(&Bsl[br]);
    }

    __builtin_amdgcn_s_setprio(1);
    #pragma unroll
    for (int c = 0; c < 2; ++c) {
      #pragma unroll
      for (int i = 0; i < 2; ++i)
        acc[i] = MFMA32(fah[c][i], fbh[c], acc[i]);
      if (THREE) {
        #pragma unroll
        for (int i = 0; i < 2; ++i)
          acc[i] = MFMA32(fah[c][i], fbl[c], acc[i]);
        #pragma unroll
        for (int i = 0; i < 2; ++i)
          acc[i] = MFMA32(fal[c][i], fbh[c], acc[i]);
      }
    }
    __builtin_amdgcn_s_setprio(0);
    __syncthreads();
  }

  // epilogue: wave covers rows [row0+wr*64, +64), cols [col0+wc*32, +32)
  {
    const int cc = col0 + wc * 32 + lr;
    const int g = cc >> 6;
    const int t3 = g >> 3, hd = g & 7;
    const int d = cc & 63;
    const float bs = bias[cc];
    #pragma unroll
    for (int i = 0; i < 2; ++i) {
      if (THREE) {
        #pragma unroll
        for (int r = 0; r < 16; ++r) {
          const int rrow = row0 + wr * 64 + i * 32 + (r & 3) + 8 * (r >> 2) + 4 * hh;
          const float x = acc[i][r] + bs;
          const size_t base = ((size_t)hd * NR_ + rrow) * D_ + d;
          if (t3 == 0) {
            half2s s = split1(x * LOG2E);   // fold log2(e) into Q
            qh[base] = s.h; ql[base] = s.l;
          } else {
            half2s s = split1(x);
            kh[base] = s.h; kl[base] = s.l;
          }
        }
      } else {
        // v: transposed layout, half4 stores along l (consecutive r&3)
        #pragma unroll
        for (int m = 0; m < 4; ++m) {
          const int rbase = row0 + wr * 64 + i * 32 + 8 * m + 4 * hh;
          const int bb = rbase >> 10;
          const int ll = rbase & 1023;
          half4 v4;
          #pragma unroll
          for (int u = 0; u < 4; ++u) v4[u] = (_Float16)(acc[i][4 * m + u] + bs);
          *(half4*)(vt + (((size_t)hd * 32 + bb) * 64 + d) * 1024 + ll) = v4;
        }
      }
    }
  }
}

// ---------------------------------------------------------------------------
// attn_mfma v9 (best measured, 212 us): fp16 mask C-init, defer-max THR=8,
// serial fdot2 l-sum, phase-major grid, double-buffered K/V.
// ---------------------------------------------------------------------------
__global__ __launch_bounds__(256, 3) void attn_mfma(
    const _Float16* __restrict__ qh, const _Float16* __restrict__ ql,
    const _Float16* __restrict__ kh, const _Float16* __restrict__ kl,
    const _Float16* __restrict__ vt,  // (8,32,64,1024) halves: [hd][b][d][l]
    const _Float16* __restrict__ mask2,  // (1024,1024) fp16, pre-scaled log2(e)
    _Float16* __restrict__ outa)      // (32768, 512) fp16
{
  constexpr int ST = 68;              // halves; 8B-aligned rows
  __shared__ _Float16 KhS[2][64 * ST];
  __shared__ _Float16 KlS[2][64 * ST];
  __shared__ _Float16 VtS[2][64 * ST];   // [d][k] row-major

  const int t    = threadIdx.x;
  const int lane = t & 63, w = t >> 6;
  const int lq   = lane & 31, hh = lane >> 5;
  const int qt = blockIdx.y;          // 0..7  (phase-major dispatch)
  const int bh = blockIdx.x;          // 0..255
  const int b  = bh & 31;
  const int hd = bh >> 5;

  const int q_row = qt * 128 + w * 32 + lq;
  const size_t headoff = (size_t)hd * NR_ * D_ + (size_t)b * L_ * D_;

  const size_t qbase = headoff + (size_t)q_row * D_;
  half8 Qhc[4], Qlc[4];
  #pragma unroll
  for (int c = 0; c < 4; ++c) {
    Qhc[c] = *(const half8*)(qh + qbase + c * 16 + hh * 8);
    Qlc[c] = *(const half8*)(ql + qbase + c * 16 + hh * 8);
  }

  const _Float16* Kph = kh + headoff;
  const _Float16* Kpl = kl + headoff;
  const _Float16* Vtp = vt + ((size_t)hd * 32 + b) * (64 * 1024);  // [d][l]
  const _Float16* mrow = mask2 + (size_t)q_row * L_;

  const int srow = t >> 2;            // 0..63
  const int soff = (t & 3) * 16;      // 0,16,32,48 halves

  float m_i = -3.0e38f, l_i = 0.f;
  f32x16 O0, O1;
  #pragma unroll
  for (int i = 0; i < 16; ++i) { O0[i] = 0.f; O1[i] = 0.f; }

  // staging registers (next K/V tile in flight)
  half8 rkh0, rkh1, rkl0, rkl1, rv0, rv1;
  {
    const size_t goff  = (size_t)srow * D_ + soff;        // K tile kt=0
    const size_t goffv = (size_t)srow * 1024 + soff;      // V^T tile kt=0
    rkh0 = *(const half8*)(Kph + goff);
    rkh1 = *(const half8*)(Kph + goff + 8);
    rkl0 = *(const half8*)(Kpl + goff);
    rkl1 = *(const half8*)(Kpl + goff + 8);
    rv0  = *(const half8*)(Vtp + goffv);
    rv1  = *(const half8*)(Vtp + goffv + 8);
  }
  {
    lds_st8(&KhS[0][srow * ST + soff],     rkh0);
    lds_st8(&KhS[0][srow * ST + soff + 8], rkh1);
    lds_st8(&KlS[0][srow * ST + soff],     rkl0);
    lds_st8(&KlS[0][srow * ST + soff + 8], rkl1);
    lds_st8(&VtS[0][srow * ST + soff],     rv0);
    lds_st8(&VtS[0][srow * ST + soff + 8], rv1);
  }

  for (int kt = 0; kt < 16; ++kt) {
    const int cur = kt & 1;

    // mask loads for this kt (fp16, issued BEFORE the barrier; C-init use)
    half4 mc[8];
    #pragma unroll
    for (int m = 0; m < 8; ++m)
      mc[m] = *(const half4*)(mrow + kt * 64 + (m >> 2) * 32 + (m & 3) * 8 + hh * 4);

    __syncthreads();   // buf[cur] complete

    // issue next-tile global loads (consumed at end-of-iter LDS write)
    if (kt + 1 < 16) {
      const size_t goff  = (size_t)((kt + 1) * 64 + srow) * D_ + soff;
      const size_t goffv = (size_t)srow * 1024 + (kt + 1) * 64 + soff;
      rkh0 = *(const half8*)(Kph + goff);
      rkh1 = *(const half8*)(Kph + goff + 8);
      rkl0 = *(const half8*)(Kpl + goff);
      rkl1 = *(const half8*)(Kpl + goff + 8);
      rv0  = *(const half8*)(Vtp + goffv);
      rv1  = *(const half8*)(Vtp + goffv + 8);
    }

    const _Float16* Kh = KhS[cur];
    const _Float16* Kl = KlS[cur];
    const _Float16* Vt = VtS[cur];

    // ---- S^T = K . Q + mask (mask converted into the MFMA C-init) ----
    f32x16 S[2];
    #pragma unroll
    for (int s2 = 0; s2 < 2; ++s2) {
      f32x16 acc;
      #pragma unroll
      for (int m = 0; m < 4; ++m) {
        half4 mv = mc[s2 * 4 + m];
        acc[4 * m + 0] = (float)mv[0];
        acc[4 * m + 1] = (float)mv[1];
        acc[4 * m + 2] = (float)mv[2];
        acc[4 * m + 3] = (float)mv[3];
      }
      #pragma unroll
      for (int c = 0; c < 4; ++c) {
        half8 ah = lds_ld8(&Kh[(s2 * 32 + lq) * ST + c * 16 + hh * 8]);
        half8 al = lds_ld8(&Kl[(s2 * 32 + lq) * ST + c * 16 + hh * 8]);
        __builtin_amdgcn_s_setprio(1);
        acc = MFMA32(ah, Qhc[c], acc);
        acc = MFMA32(ah, Qlc[c], acc);
        acc = MFMA32(al, Qhc[c], acc);
        __builtin_amdgcn_s_setprio(0);
      }
      S[s2] = acc;
    }

    // ---- tile max (max3-friendly tree) ----
    float pm[8];
    #pragma unroll
    for (int g4 = 0; g4 < 8; ++g4) {
      const int s2 = g4 >> 2, m = g4 & 3;
      pm[g4] = fmaxf(fmaxf(S[s2][4 * m + 0], S[s2][4 * m + 1]),
                     fmaxf(S[s2][4 * m + 2], S[s2][4 * m + 3]));
    }
    float tmax = fmaxf(fmaxf(fmaxf(pm[0], pm[1]), fmaxf(pm[2], pm[3])),
                       fmaxf(fmaxf(pm[4], pm[5]), fmaxf(pm[6], pm[7])));
    tmax = fmaxf(tmax, __shfl_xor(tmax, 32, 64));

    // ---- defer-max: only rescale when the tile max grows past m_i + 8 ----
    if (!__all(tmax - m_i <= 8.0f)) {
      float mn = fmaxf(m_i, tmax);
      float sc = exp2f(m_i - mn);
      m_i = mn;
      l_i *= sc;
      O0 = O0 * sc;
      O1 = O1 * sc;
    }

    #pragma unroll
    for (int s2 = 0; s2 < 2; ++s2)
      #pragma unroll
      for (int r = 0; r < 16; ++r)
        S[s2][r] = exp2f(S[s2][r] - m_i);

    // ---- pack P -> fp16 words; l-sum over the PACKED values ----
    unsigned pw[4][4];
    #pragma unroll
    for (int kc = 0; kc < 4; ++kc) {
      const int s2 = kc >> 1, a2 = kc & 1;
      pw[kc][0] = pkh(S[s2][8 * a2 + 0], S[s2][8 * a2 + 1]);
      pw[kc][1] = pkh(S[s2][8 * a2 + 2], S[s2][8 * a2 + 3]);
      pw[kc][2] = pkh(S[s2][8 * a2 + 4], S[s2][8 * a2 + 5]);
      pw[kc][3] = pkh(S[s2][8 * a2 + 6], S[s2][8 * a2 + 7]);
    }
    float rs = 0.f;
#if __has_builtin(__builtin_amdgcn_fdot2)
    {
      half2v one2;
      one2[0] = (_Float16)1.0f;
      one2[1] = (_Float16)1.0f;
      #pragma unroll
      for (int kc = 0; kc < 4; ++kc)
        #pragma unroll
        for (int u = 0; u < 4; ++u)
          rs = __builtin_amdgcn_fdot2(
              __builtin_bit_cast(half2v, pw[kc][u]), one2, rs, false);
    }
#else
    #pragma unroll
    for (int s2 = 0; s2 < 2; ++s2)
      #pragma unroll
      for (int r = 0; r < 16; ++r) rs += S[s2][r];
#endif
    rs += __shfl_xor(rs, 32, 64);
    l_i += rs;

    // ---- O^T += V^T . P^T ; P^T frags via permlane32_swap ----
    #pragma unroll
    for (int kc = 0; kc < 4; ++kc) {
      uint2v r0 = __builtin_amdgcn_permlane32_swap(pw[kc][0], pw[kc][2], false, false);
      uint2v r1 = __builtin_amdgcn_permlane32_swap(pw[kc][1], pw[kc][3], false, false);
      uint4v wv;
      wv.x = r0.x; wv.y = r1.x; wv.z = r0.y; wv.w = r1.y;
      half8 pfrag = __builtin_bit_cast(half8, wv);
      half8 va = lds_ld8(&Vt[lq * ST + kc * 16 + hh * 8]);
      half8 vb = lds_ld8(&Vt[(32 + lq) * ST + kc * 16 + hh * 8]);
      __builtin_amdgcn_s_setprio(1);
      O0 = MFMA32(va, pfrag, O0);
      O1 = MFMA32(vb, pfrag, O1);
      __builtin_amdgcn_s_setprio(0);
    }

    // ---- write next tile into the other buffer ----
    if (kt + 1 < 16) {
      _Float16* Kh2 = KhS[cur ^ 1];
      _Float16* Kl2 = KlS[cur ^ 1];
      _Float16* Vt2 = VtS[cur ^ 1];
      lds_st8(&Kh2[srow * ST + soff],     rkh0);
      lds_st8(&Kh2[srow * ST + soff + 8], rkh1);
      lds_st8(&Kl2[srow * ST + soff],     rkl0);
      lds_st8(&Kl2[srow * ST + soff + 8], rkl1);
      lds_st8(&Vt2[srow * ST + soff],     rv0);
      lds_st8(&Vt2[srow * ST + soff + 8], rv1);
    }
  }

  float inv = 1.0f / l_i;
  _Float16* orow = outa + ((size_t)b * L_ + q_row) * M_ + hd * 64;
  #pragma unroll
  for (int m = 0; m < 4; ++m) {
    half4 v0 = {(_Float16)(O0[4 * m + 0] * inv), (_Float16)(O0[4 * m + 1] * inv),
                (_Float16)(O0[4 * m + 2] * inv), (_Float16)(O0[4 * m + 3] * inv)};
    *(half4*)(orow + m * 8 + hh * 4) = v0;
    half4 v1 = {(_Float16)(O1[4 * m + 0] * inv), (_Float16)(O1[4 * m + 1] * inv),
                (_Float16)(O1[4 * m + 2] * inv), (_Float16)(O1[4 * m + 3] * inv)};
    *(half4*)(orow + 32 + m * 8 + hh * 4) = v1;
  }
}

// ---------------------------------------------------------------------------
// post_mfma (frozen): out(32768x512 f32) = attn_h(f16) x pwt(f16) + bias
// ---------------------------------------------------------------------------
__global__ __launch_bounds__(256, 2) void post_mfma(
    const _Float16* __restrict__ Ah, const _Float16* __restrict__ Wt,
    const float* __restrict__ bias, float* __restrict__ C)
{
  __shared__ _Float16 Ash[128 * 36];
  __shared__ _Float16 Bsh[128 * 36];

  const int t = threadIdx.x;
  const int lane = t & 63, w = t >> 6;
  const int wr = w >> 1, wc = w & 1;
  const int lr = lane & 31, hh = lane >> 5;
  const int col0 = blockIdx.x * 128;
  const int row0 = blockIdx.y * 128;

  const int sr = t >> 2;
  const int so = (t & 3) * 8;

  f32x16 acc[2][2];
  #pragma unroll
  for (int i = 0; i < 2; ++i)
    #pragma unroll
    for (int j = 0; j < 2; ++j)
      #pragma unroll
      for (int r = 0; r < 16; ++r) acc[i][j][r] = 0.f;

  half8 rah[2], rbh[2];
  #pragma unroll
  for (int i = 0; i < 2; ++i) {
    rah[i] = *(const half8*)(Ah + (size_t)(row0 + sr + i * 64) * M_ + so);
    rbh[i] = *(const half8*)(Wt + (size_t)(col0 + sr + i * 64) * M_ + so);
  }

  for (int k0 = 0; k0 < M_; k0 += 32) {
    #pragma unroll
    for (int i = 0; i < 2; ++i) {
      int r = sr + i * 64;
      lds_st8(&Ash[r * 36 + so], rah[i]);
      lds_st8(&Bsh[r * 36 + so], rbh[i]);
    }
    __syncthreads();
    if (k0 + 32 < M_) {
      #pragma unroll
      for (int i = 0; i < 2; ++i) {
        rah[i] = *(const half8*)(Ah + (size_t)(row0 + sr + i * 64) * M_ + k0 + 32 + so);
        rbh[i] = *(const half8*)(Wt + (size_t)(col0 + sr + i * 64) * M_ + k0 + 32 + so);
      }
    }
    half8 fah[2][2], fbh[2][2];
    #pragma unroll
    for (int c = 0; c < 2; ++c)
      #pragma unroll
      for (int i = 0; i < 2; ++i) {
        fah[c][i] = lds_ld8(&Ash[(wr * 64 + i * 32 + lr) * 36 + c * 16 + hh * 8]);
        fbh[c][i] = lds_ld8(&Bsh[(wc * 64 + i * 32 + lr) * 36 + c * 16 + hh * 8]);
      }
    __builtin_amdgcn_s_setprio(1);
    #pragma unroll
    for (int c = 0; c < 2; ++c)
      #pragma unroll
      for (int i = 0; i < 2; ++i)
        #pragma unroll
        for (int j = 0; j < 2; ++j)
          acc[i][j] = MFMA32(fah[c][i], fbh[c][j], acc[i][j]);
    __builtin_amdgcn_s_setprio(0);
    __syncthreads();
  }

  #pragma unroll
  for (int j = 0; j < 2; ++j) {
    const int cc = col0 + wc * 64 + j * 32 + lr;
    const float bs = bias[cc];
    #pragma unroll
    for (int i = 0; i < 2; ++i)
      #pragma unroll
      for (int r = 0; r < 16; ++r) {
        const int rrow = row0 + wr * 64 + i * 32 + (r & 3) + 8 * (r >> 2) + 4 * hh;
        C[(size_t)rrow * M_ + cc] = acc[i][j][r] + bs;
      }
  }
}

extern "C" void kernel_launch(void* const* d_in, const int* in_sizes, int n_in,
                              void* d_out, int out_size, void* d_ws, size_t ws_size,
                              hipStream_t stream) {
  const float* inp    = (const float*)d_in[0];
  const float* mask   = (const float*)d_in[1];
  const float* pre_w  = (const float*)d_in[2];
  const float* pre_b  = (const float*)d_in[3];
  const float* post_w = (const float*)d_in[4];
  const float* post_b = (const float*)d_in[5];
  float* out = (float*)d_out;

  const size_t HNE = (size_t)H_ * NR_ * D_;   // 16,777,216

  _Float16* w2t_hi = (_Float16*)d_ws;              // (1536,512)
  _Float16* w2t_lo = w2t_hi + (size_t)1536 * M_;
  _Float16* pwt    = w2t_lo + (size_t)1536 * M_;   // (512,512)
  _Float16* q_hi   = pwt + (size_t)M_ * M_;
  _Float16* q_lo   = q_hi + HNE;
  _Float16* k_hi   = q_lo + HNE;
  _Float16* k_lo   = k_hi + HNE;
  _Float16* v_t    = k_lo + HNE;              // (8,32,64,1024) transposed v
  _Float16* mask2  = v_t + HNE;               // (1024,1024) fp16
  _Float16* attn_h = mask2 + (size_t)L_ * L_; // (32768,512) fp16

  prep<<<1024, 256, 0, stream>>>(pre_w, w2t_hi, w2t_lo, post_w, pwt, mask, mask2);

  qkv_fused<<<3072, 512, 0, stream>>>(
      inp, w2t_hi, w2t_lo, pre_b, q_hi, q_lo, k_hi, k_lo, v_t);

  attn_mfma<<<dim3(256, 8), 256, 0, stream>>>(q_hi, q_lo, k_hi, k_lo, v_t,
                                              mask2, attn_h);

  post_mfma<<<dim3(4, 256), 256, 0, stream>>>(attn_h, pwt, post_b, out);
}